// Round 1
// baseline (3532.779 us; speedup 1.0000x reference)
//
#include <hip/hip_runtime.h>
#include <math.h>

#define NN 100000
#define NE 800000
#define D 128

// Workspace layout (bytes)
constexpr size_t OFF_DEG = 0;                       // float[NN]
constexpr size_t OFF_AGG = 524288;                  // float[NN*D]
constexpr size_t SZ_NODE = (size_t)NN * D * sizeof(float);  // 51,200,000
constexpr size_t OFF_H1  = OFF_AGG + SZ_NODE;
constexpr size_t OFF_H2  = OFF_H1 + SZ_NODE;

// ---------------- degree ----------------
__global__ __launch_bounds__(256) void k_deg(const int* __restrict__ dst,
                                             float* __restrict__ deg) {
    int e = blockIdx.x * 256 + threadIdx.x;
    if (e < NE) atomicAdd(&deg[dst[e]], 1.0f);
}

// ---------------- scatter-add: agg[dst] += feat[src] ----------------
// 32 threads per edge, float4 each
__global__ __launch_bounds__(256) void k_scatter(const float* __restrict__ feat,
                                                 const int* __restrict__ src,
                                                 const int* __restrict__ dst,
                                                 float* __restrict__ agg) {
    int t = blockIdx.x * 256 + threadIdx.x;
    int e = t >> 5, q = t & 31;
    if (e >= NE) return;
    int s = src[e], d = dst[e];
    const float4 v = *(const float4*)&feat[(size_t)s * D + q * 4];
    float* a = &agg[(size_t)d * D + q * 4];
    atomicAdd(a + 0, v.x);
    atomicAdd(a + 1, v.y);
    atomicAdd(a + 2, v.z);
    atomicAdd(a + 3, v.w);
}

// ---------------- SAGE linear: h = relu(norm(agg)@Wl^T + bl + x@Wr^T) -------
// 32 rows x 128 cols per block (256 threads). Per thread: 4 rows x 4 cols.
__global__ __launch_bounds__(256) void k_conv(const float* __restrict__ agg,
                                              const float* __restrict__ deg,
                                              const float* __restrict__ xin,
                                              const float* __restrict__ Wl,
                                              const float* __restrict__ bl,
                                              const float* __restrict__ Wr,
                                              float* __restrict__ hout) {
    __shared__ __align__(16) float As[32][132];   // A rows (full K=128)
    __shared__ __align__(16) float Ws[32][132];   // Ws[kk][c], transposed W k-slab
    const int tid = threadIdx.x;
    const int n0  = blockIdx.x * 32;
    const int cc  = tid & 31;   // col group: cols cc*4..cc*4+3
    const int er  = tid >> 5;   // row group: rows er*4..er*4+3
    float acc[4][4] = {};

    for (int p = 0; p < 2; ++p) {
        const float* A = p ? xin : agg;
        const float* W = p ? Wr : Wl;
        __syncthreads();
        // stage 32 rows of A (apply 1/deg on phase 0)
        #pragma unroll
        for (int i = 0; i < 4; ++i) {
            int idx = tid + 256 * i;            // 0..1023
            int r = idx >> 5, q = idx & 31;
            int n = n0 + r;
            float4 v = *(const float4*)&A[(size_t)n * D + q * 4];
            if (p == 0) {
                float inv = 1.0f / fmaxf(deg[n], 1.0f);
                v.x *= inv; v.y *= inv; v.z *= inv; v.w *= inv;
            }
            *(float4*)&As[r][q * 4] = v;
        }
        for (int k0 = 0; k0 < D; k0 += 32) {
            __syncthreads();
            // stage transposed W slab: Ws[kk][c] = W[c][k0+kk]
            #pragma unroll
            for (int i = 0; i < 4; ++i) {
                int idx = tid + 256 * i;        // 0..1023
                int c = idx >> 3, kq = idx & 7;
                float4 w = *(const float4*)&W[(size_t)c * D + k0 + kq * 4];
                Ws[kq * 4 + 0][c] = w.x;
                Ws[kq * 4 + 1][c] = w.y;
                Ws[kq * 4 + 2][c] = w.z;
                Ws[kq * 4 + 3][c] = w.w;
            }
            __syncthreads();
            #pragma unroll
            for (int kk = 0; kk < 32; kk += 4) {
                float4 w0 = *(const float4*)&Ws[kk + 0][cc * 4];
                float4 w1 = *(const float4*)&Ws[kk + 1][cc * 4];
                float4 w2 = *(const float4*)&Ws[kk + 2][cc * 4];
                float4 w3 = *(const float4*)&Ws[kk + 3][cc * 4];
                #pragma unroll
                for (int e = 0; e < 4; ++e) {
                    float4 a = *(const float4*)&As[er * 4 + e][k0 + kk];
                    acc[e][0] += a.x * w0.x + a.y * w1.x + a.z * w2.x + a.w * w3.x;
                    acc[e][1] += a.x * w0.y + a.y * w1.y + a.z * w2.y + a.w * w3.y;
                    acc[e][2] += a.x * w0.z + a.y * w1.z + a.z * w2.z + a.w * w3.z;
                    acc[e][3] += a.x * w0.w + a.y * w1.w + a.z * w2.w + a.w * w3.w;
                }
            }
        }
    }
    const float4 bb = *(const float4*)&bl[cc * 4];
    #pragma unroll
    for (int e = 0; e < 4; ++e) {
        int n = n0 + er * 4 + e;
        float4 o;
        o.x = fmaxf(acc[e][0] + bb.x, 0.0f);
        o.y = fmaxf(acc[e][1] + bb.y, 0.0f);
        o.z = fmaxf(acc[e][2] + bb.z, 0.0f);
        o.w = fmaxf(acc[e][3] + bb.w, 0.0f);
        *(float4*)&hout[(size_t)n * D + cc * 4] = o;
    }
}

// ---------------- generic node linear: out = A @ W[:, koff:koff+128]^T (+bias)
__global__ __launch_bounds__(256) void k_lin(const float* __restrict__ Ain,
                                             const float* __restrict__ W,
                                             int wstride, int koff,
                                             const float* __restrict__ bias,
                                             float* __restrict__ outp) {
    __shared__ __align__(16) float As[32][132];
    __shared__ __align__(16) float Ws[32][132];
    const int tid = threadIdx.x;
    const int n0  = blockIdx.x * 32;
    const int cc  = tid & 31;
    const int er  = tid >> 5;
    float acc[4][4] = {};

    #pragma unroll
    for (int i = 0; i < 4; ++i) {
        int idx = tid + 256 * i;
        int r = idx >> 5, q = idx & 31;
        int n = n0 + r;
        float4 v = *(const float4*)&Ain[(size_t)n * D + q * 4];
        *(float4*)&As[r][q * 4] = v;
    }
    for (int k0 = 0; k0 < D; k0 += 32) {
        __syncthreads();
        #pragma unroll
        for (int i = 0; i < 4; ++i) {
            int idx = tid + 256 * i;
            int c = idx >> 3, kq = idx & 7;
            float4 w = *(const float4*)&W[(size_t)c * wstride + koff + k0 + kq * 4];
            Ws[kq * 4 + 0][c] = w.x;
            Ws[kq * 4 + 1][c] = w.y;
            Ws[kq * 4 + 2][c] = w.z;
            Ws[kq * 4 + 3][c] = w.w;
        }
        __syncthreads();
        #pragma unroll
        for (int kk = 0; kk < 32; kk += 4) {
            float4 w0 = *(const float4*)&Ws[kk + 0][cc * 4];
            float4 w1 = *(const float4*)&Ws[kk + 1][cc * 4];
            float4 w2 = *(const float4*)&Ws[kk + 2][cc * 4];
            float4 w3 = *(const float4*)&Ws[kk + 3][cc * 4];
            #pragma unroll
            for (int e = 0; e < 4; ++e) {
                float4 a = *(const float4*)&As[er * 4 + e][k0 + kk];
                acc[e][0] += a.x * w0.x + a.y * w1.x + a.z * w2.x + a.w * w3.x;
                acc[e][1] += a.x * w0.y + a.y * w1.y + a.z * w2.y + a.w * w3.y;
                acc[e][2] += a.x * w0.z + a.y * w1.z + a.z * w2.z + a.w * w3.z;
                acc[e][3] += a.x * w0.w + a.y * w1.w + a.z * w2.w + a.w * w3.w;
            }
        }
    }
    float4 bb = make_float4(0.f, 0.f, 0.f, 0.f);
    if (bias) bb = *(const float4*)&bias[cc * 4];
    #pragma unroll
    for (int e = 0; e < 4; ++e) {
        int n = n0 + er * 4 + e;
        float4 o;
        o.x = acc[e][0] + bb.x;
        o.y = acc[e][1] + bb.y;
        o.z = acc[e][2] + bb.z;
        o.w = acc[e][3] + bb.w;
        *(float4*)&outp[(size_t)n * D + cc * 4] = o;
    }
}

// ---------------- edge finalize: sigmoid(wm2 . relu(U[s]+V[d]) + bm2) -------
// 16 threads per edge
__global__ __launch_bounds__(256) void k_edge_out(const float* __restrict__ U,
                                                  const float* __restrict__ V,
                                                  const int* __restrict__ src,
                                                  const int* __restrict__ dst,
                                                  const float* __restrict__ wm2,
                                                  const float* __restrict__ bm2,
                                                  float* __restrict__ out) {
    int t = blockIdx.x * 256 + threadIdx.x;
    int e = t >> 4, q = t & 15;
    if (e >= NE) return;
    int s = src[e], d = dst[e];
    float part = 0.0f;
    #pragma unroll
    for (int i = 0; i < 2; ++i) {
        int k = q * 8 + i * 4;
        float4 u = *(const float4*)&U[(size_t)s * D + k];
        float4 v = *(const float4*)&V[(size_t)d * D + k];
        float4 w = *(const float4*)&wm2[k];
        part += fmaxf(u.x + v.x, 0.0f) * w.x + fmaxf(u.y + v.y, 0.0f) * w.y +
                fmaxf(u.z + v.z, 0.0f) * w.z + fmaxf(u.w + v.w, 0.0f) * w.w;
    }
    #pragma unroll
    for (int off = 1; off < 16; off <<= 1) part += __shfl_xor(part, off);
    if (q == 0) out[e] = 1.0f / (1.0f + expf(-(part + bm2[0])));
}

extern "C" void kernel_launch(void* const* d_in, const int* in_sizes, int n_in,
                              void* d_out, int out_size, void* d_ws, size_t ws_size,
                              hipStream_t stream) {
    const float* x   = (const float*)d_in[0];
    const int*   ei  = (const int*)d_in[1];
    const int*   src = ei;
    const int*   dst = ei + NE;
    const float* W1l = (const float*)d_in[2];
    const float* b1l = (const float*)d_in[3];
    const float* W1r = (const float*)d_in[4];
    const float* W2l = (const float*)d_in[5];
    const float* b2l = (const float*)d_in[6];
    const float* W2r = (const float*)d_in[7];
    const float* Wm1 = (const float*)d_in[8];
    const float* bm1 = (const float*)d_in[9];
    const float* Wm2 = (const float*)d_in[10];
    const float* bm2 = (const float*)d_in[11];
    float* out = (float*)d_out;

    char* ws = (char*)d_ws;
    float* deg = (float*)(ws + OFF_DEG);
    float* agg = (float*)(ws + OFF_AGG);
    float* h1  = (float*)(ws + OFF_H1);
    float* h2  = (float*)(ws + OFF_H2);
    float* U   = agg;  // reuse after conv2 consumed agg
    float* V   = h1;   // reuse after conv2 consumed h1

    // zero deg + agg
    hipMemsetAsync(ws, 0, OFF_AGG + SZ_NODE, stream);
    k_deg<<<NE / 256, 256, 0, stream>>>(dst, deg);
    k_scatter<<<(NE * 32) / 256, 256, 0, stream>>>(x, src, dst, agg);
    k_conv<<<NN / 32, 256, 0, stream>>>(agg, deg, x, W1l, b1l, W1r, h1);
    hipMemsetAsync(ws + OFF_AGG, 0, SZ_NODE, stream);
    k_scatter<<<(NE * 32) / 256, 256, 0, stream>>>(h1, src, dst, agg);
    k_conv<<<NN / 32, 256, 0, stream>>>(agg, deg, h1, W2l, b2l, W2r, h2);
    k_lin<<<NN / 32, 256, 0, stream>>>(h2, Wm1, 2 * D, 0, bm1, U);
    k_lin<<<NN / 32, 256, 0, stream>>>(h2, Wm1, 2 * D, D, nullptr, V);
    k_edge_out<<<(NE * 16) / 256, 256, 0, stream>>>(U, V, src, dst, Wm2, bm2, out);
}

// Round 2
// 1159.889 us; speedup vs baseline: 3.0458x; 3.0458x over previous
//
#include <hip/hip_runtime.h>
#include <math.h>

#define NN 100000
#define NE 800000
#define D 128

// Workspace layout (bytes)
constexpr size_t OFF_RS  = 0;                                // int row_start[NN+1]
constexpr size_t OFF_AGG = 524288;                           // float[NN*D]
constexpr size_t SZ_NODE = (size_t)NN * D * sizeof(float);   // 51,200,000
constexpr size_t OFF_H1  = OFF_AGG + SZ_NODE;
constexpr size_t OFF_H2  = OFF_H1 + SZ_NODE;
constexpr size_t OFF_RE  = OFF_H2 + SZ_NODE;                 // int cursor/row_end[NN]
constexpr size_t OFF_SRC = OFF_RE + 524288;                  // int src_sorted[NE]

// ---------------- CSR build ----------------
__global__ __launch_bounds__(256) void k_hist(const int* __restrict__ dst,
                                              int* __restrict__ cnt) {
    int e = blockIdx.x * 256 + threadIdx.x;
    if (e < NE) atomicAdd(&cnt[dst[e]], 1);
}

// single block, 1024 threads: exclusive scan of cnt[0..NN) -> rs, cursor(cnt)=rs
__global__ __launch_bounds__(1024) void k_scan(int* __restrict__ cnt,
                                               int* __restrict__ rs) {
    __shared__ int part[1024];
    const int t = threadIdx.x;
    const int CH = (NN + 1023) / 1024;   // 98
    int lo = t * CH, hi = lo + CH;
    if (hi > NN) hi = NN;
    int s = 0;
    for (int i = lo; i < hi; ++i) s += cnt[i];
    part[t] = s;
    __syncthreads();
    for (int off = 1; off < 1024; off <<= 1) {
        int v = (t >= off) ? part[t - off] : 0;
        __syncthreads();
        part[t] += v;
        __syncthreads();
    }
    int pre = (t == 0) ? 0 : part[t - 1];
    for (int i = lo; i < hi; ++i) {
        int c = cnt[i];
        rs[i] = pre;
        cnt[i] = pre;   // cursor init
        pre += c;
    }
    if (t == 0) rs[NN] = NE;
}

__global__ __launch_bounds__(256) void k_scatter_idx(const int* __restrict__ src,
                                                     const int* __restrict__ dst,
                                                     int* __restrict__ cur,
                                                     int* __restrict__ srcs) {
    int e = blockIdx.x * 256 + threadIdx.x;
    if (e < NE) {
        int d = dst[e];
        int pos = atomicAdd(&cur[d], 1);
        srcs[pos] = src[e];
    }
}

// ---------------- gather-aggregate (mean): agg[n] = mean_{j in N(n)} feat[srcs[j]]
// 32 threads per node (float4 each), 8 nodes per block
__global__ __launch_bounds__(256) void k_agg(const float* __restrict__ feat,
                                             const int* __restrict__ rs,
                                             const int* __restrict__ re,
                                             const int* __restrict__ srcs,
                                             float* __restrict__ agg) {
    int t = blockIdx.x * 256 + threadIdx.x;
    int n = t >> 5, q = t & 31;
    if (n >= NN) return;
    int b = rs[n], eend = re[n];
    float4 acc = make_float4(0.f, 0.f, 0.f, 0.f);
    int sidx = (b < eend) ? srcs[b] : 0;
    for (int j = b; j < eend; ++j) {
        int nxt = (j + 1 < eend) ? srcs[j + 1] : 0;
        const float4 v = *(const float4*)&feat[(size_t)sidx * D + q * 4];
        acc.x += v.x; acc.y += v.y; acc.z += v.z; acc.w += v.w;
        sidx = nxt;
    }
    float inv = 1.0f / fmaxf((float)(eend - b), 1.0f);
    acc.x *= inv; acc.y *= inv; acc.z *= inv; acc.w *= inv;
    *(float4*)&agg[(size_t)n * D + q * 4] = acc;
}

// ---------------- SAGE linear: h = relu(agg@Wl^T + bl + x@Wr^T) -------
// 32 rows x 128 cols per block (256 threads). Per thread: 4 rows x 4 cols.
__global__ __launch_bounds__(256) void k_conv(const float* __restrict__ agg,
                                              const float* __restrict__ xin,
                                              const float* __restrict__ Wl,
                                              const float* __restrict__ bl,
                                              const float* __restrict__ Wr,
                                              float* __restrict__ hout) {
    __shared__ __align__(16) float As[32][132];
    __shared__ __align__(16) float Ws[32][132];
    const int tid = threadIdx.x;
    const int n0  = blockIdx.x * 32;
    const int cc  = tid & 31;
    const int er  = tid >> 5;
    float acc[4][4] = {};

    for (int p = 0; p < 2; ++p) {
        const float* A = p ? xin : agg;
        const float* W = p ? Wr : Wl;
        __syncthreads();
        #pragma unroll
        for (int i = 0; i < 4; ++i) {
            int idx = tid + 256 * i;
            int r = idx >> 5, q = idx & 31;
            float4 v = *(const float4*)&A[(size_t)(n0 + r) * D + q * 4];
            *(float4*)&As[r][q * 4] = v;
        }
        for (int k0 = 0; k0 < D; k0 += 32) {
            __syncthreads();
            #pragma unroll
            for (int i = 0; i < 4; ++i) {
                int idx = tid + 256 * i;
                int c = idx >> 3, kq = idx & 7;
                float4 w = *(const float4*)&W[(size_t)c * D + k0 + kq * 4];
                Ws[kq * 4 + 0][c] = w.x;
                Ws[kq * 4 + 1][c] = w.y;
                Ws[kq * 4 + 2][c] = w.z;
                Ws[kq * 4 + 3][c] = w.w;
            }
            __syncthreads();
            #pragma unroll
            for (int kk = 0; kk < 32; kk += 4) {
                float4 w0 = *(const float4*)&Ws[kk + 0][cc * 4];
                float4 w1 = *(const float4*)&Ws[kk + 1][cc * 4];
                float4 w2 = *(const float4*)&Ws[kk + 2][cc * 4];
                float4 w3 = *(const float4*)&Ws[kk + 3][cc * 4];
                #pragma unroll
                for (int e = 0; e < 4; ++e) {
                    float4 a = *(const float4*)&As[er * 4 + e][k0 + kk];
                    acc[e][0] += a.x * w0.x + a.y * w1.x + a.z * w2.x + a.w * w3.x;
                    acc[e][1] += a.x * w0.y + a.y * w1.y + a.z * w2.y + a.w * w3.y;
                    acc[e][2] += a.x * w0.z + a.y * w1.z + a.z * w2.z + a.w * w3.z;
                    acc[e][3] += a.x * w0.w + a.y * w1.w + a.z * w2.w + a.w * w3.w;
                }
            }
        }
    }
    const float4 bb = *(const float4*)&bl[cc * 4];
    #pragma unroll
    for (int e = 0; e < 4; ++e) {
        int n = n0 + er * 4 + e;
        float4 o;
        o.x = fmaxf(acc[e][0] + bb.x, 0.0f);
        o.y = fmaxf(acc[e][1] + bb.y, 0.0f);
        o.z = fmaxf(acc[e][2] + bb.z, 0.0f);
        o.w = fmaxf(acc[e][3] + bb.w, 0.0f);
        *(float4*)&hout[(size_t)n * D + cc * 4] = o;
    }
}

// ---------------- generic node linear: out = A @ W[:, koff:koff+128]^T (+bias)
__global__ __launch_bounds__(256) void k_lin(const float* __restrict__ Ain,
                                             const float* __restrict__ W,
                                             int wstride, int koff,
                                             const float* __restrict__ bias,
                                             float* __restrict__ outp) {
    __shared__ __align__(16) float As[32][132];
    __shared__ __align__(16) float Ws[32][132];
    const int tid = threadIdx.x;
    const int n0  = blockIdx.x * 32;
    const int cc  = tid & 31;
    const int er  = tid >> 5;
    float acc[4][4] = {};

    #pragma unroll
    for (int i = 0; i < 4; ++i) {
        int idx = tid + 256 * i;
        int r = idx >> 5, q = idx & 31;
        float4 v = *(const float4*)&Ain[(size_t)(n0 + r) * D + q * 4];
        *(float4*)&As[r][q * 4] = v;
    }
    for (int k0 = 0; k0 < D; k0 += 32) {
        __syncthreads();
        #pragma unroll
        for (int i = 0; i < 4; ++i) {
            int idx = tid + 256 * i;
            int c = idx >> 3, kq = idx & 7;
            float4 w = *(const float4*)&W[(size_t)c * wstride + koff + k0 + kq * 4];
            Ws[kq * 4 + 0][c] = w.x;
            Ws[kq * 4 + 1][c] = w.y;
            Ws[kq * 4 + 2][c] = w.z;
            Ws[kq * 4 + 3][c] = w.w;
        }
        __syncthreads();
        #pragma unroll
        for (int kk = 0; kk < 32; kk += 4) {
            float4 w0 = *(const float4*)&Ws[kk + 0][cc * 4];
            float4 w1 = *(const float4*)&Ws[kk + 1][cc * 4];
            float4 w2 = *(const float4*)&Ws[kk + 2][cc * 4];
            float4 w3 = *(const float4*)&Ws[kk + 3][cc * 4];
            #pragma unroll
            for (int e = 0; e < 4; ++e) {
                float4 a = *(const float4*)&As[er * 4 + e][k0 + kk];
                acc[e][0] += a.x * w0.x + a.y * w1.x + a.z * w2.x + a.w * w3.x;
                acc[e][1] += a.x * w0.y + a.y * w1.y + a.z * w2.y + a.w * w3.y;
                acc[e][2] += a.x * w0.z + a.y * w1.z + a.z * w2.z + a.w * w3.z;
                acc[e][3] += a.x * w0.w + a.y * w1.w + a.z * w2.w + a.w * w3.w;
            }
        }
    }
    float4 bb = make_float4(0.f, 0.f, 0.f, 0.f);
    if (bias) bb = *(const float4*)&bias[cc * 4];
    #pragma unroll
    for (int e = 0; e < 4; ++e) {
        int n = n0 + er * 4 + e;
        float4 o;
        o.x = acc[e][0] + bb.x;
        o.y = acc[e][1] + bb.y;
        o.z = acc[e][2] + bb.z;
        o.w = acc[e][3] + bb.w;
        *(float4*)&outp[(size_t)n * D + cc * 4] = o;
    }
}

// ---------------- edge finalize: sigmoid(wm2 . relu(U[s]+V[d]) + bm2) -------
__global__ __launch_bounds__(256) void k_edge_out(const float* __restrict__ U,
                                                  const float* __restrict__ V,
                                                  const int* __restrict__ src,
                                                  const int* __restrict__ dst,
                                                  const float* __restrict__ wm2,
                                                  const float* __restrict__ bm2,
                                                  float* __restrict__ out) {
    int t = blockIdx.x * 256 + threadIdx.x;
    int e = t >> 4, q = t & 15;
    if (e >= NE) return;
    int s = src[e], d = dst[e];
    float part = 0.0f;
    #pragma unroll
    for (int i = 0; i < 2; ++i) {
        int k = q * 8 + i * 4;
        float4 u = *(const float4*)&U[(size_t)s * D + k];
        float4 v = *(const float4*)&V[(size_t)d * D + k];
        float4 w = *(const float4*)&wm2[k];
        part += fmaxf(u.x + v.x, 0.0f) * w.x + fmaxf(u.y + v.y, 0.0f) * w.y +
                fmaxf(u.z + v.z, 0.0f) * w.z + fmaxf(u.w + v.w, 0.0f) * w.w;
    }
    #pragma unroll
    for (int off = 1; off < 16; off <<= 1) part += __shfl_xor(part, off);
    if (q == 0) out[e] = 1.0f / (1.0f + expf(-(part + bm2[0])));
}

extern "C" void kernel_launch(void* const* d_in, const int* in_sizes, int n_in,
                              void* d_out, int out_size, void* d_ws, size_t ws_size,
                              hipStream_t stream) {
    const float* x   = (const float*)d_in[0];
    const int*   ei  = (const int*)d_in[1];
    const int*   src = ei;
    const int*   dst = ei + NE;
    const float* W1l = (const float*)d_in[2];
    const float* b1l = (const float*)d_in[3];
    const float* W1r = (const float*)d_in[4];
    const float* W2l = (const float*)d_in[5];
    const float* b2l = (const float*)d_in[6];
    const float* W2r = (const float*)d_in[7];
    const float* Wm1 = (const float*)d_in[8];
    const float* bm1 = (const float*)d_in[9];
    const float* Wm2 = (const float*)d_in[10];
    const float* bm2 = (const float*)d_in[11];
    float* out = (float*)d_out;

    char* ws = (char*)d_ws;
    int*   rs   = (int*)(ws + OFF_RS);
    float* agg  = (float*)(ws + OFF_AGG);
    float* h1   = (float*)(ws + OFF_H1);
    float* h2   = (float*)(ws + OFF_H2);
    int*   re   = (int*)(ws + OFF_RE);    // cursor during build, row_end after
    int*   srcs = (int*)(ws + OFF_SRC);
    float* U    = agg;  // reuse after conv2 consumed agg
    float* V    = h1;   // reuse after conv2 consumed h1

    // CSR build (once per call; replay-safe since re is re-zeroed here)
    hipMemsetAsync(re, 0, NN * sizeof(int), stream);
    k_hist<<<NE / 256, 256, 0, stream>>>(dst, re);
    k_scan<<<1, 1024, 0, stream>>>(re, rs);
    k_scatter_idx<<<NE / 256, 256, 0, stream>>>(src, dst, re, srcs);

    k_agg<<<(NN * 32 + 255) / 256, 256, 0, stream>>>(x, rs, re, srcs, agg);
    k_conv<<<NN / 32, 256, 0, stream>>>(agg, x, W1l, b1l, W1r, h1);
    k_agg<<<(NN * 32 + 255) / 256, 256, 0, stream>>>(h1, rs, re, srcs, agg);
    k_conv<<<NN / 32, 256, 0, stream>>>(agg, h1, W2l, b2l, W2r, h2);
    k_lin<<<NN / 32, 256, 0, stream>>>(h2, Wm1, 2 * D, 0, bm1, U);
    k_lin<<<NN / 32, 256, 0, stream>>>(h2, Wm1, 2 * D, D, nullptr, V);
    k_edge_out<<<(NE * 16) / 256, 256, 0, stream>>>(U, V, src, dst, Wm2, bm2, out);
}

// Round 3
// 409.234 us; speedup vs baseline: 8.6327x; 2.8343x over previous
//
#include <hip/hip_runtime.h>
#include <math.h>

#define NN 100000
#define NE 800000
#define D 128

typedef __attribute__((ext_vector_type(8))) short bf16x8;
typedef __attribute__((ext_vector_type(8))) unsigned short u16x8;
typedef __attribute__((ext_vector_type(4))) float f32x4;

// ---- workspace layout (bytes) ----
constexpr size_t OFF_RS  = 0;                        // int[NN+1]
constexpr size_t OFF_CNT = 512 * 1024;               // int[NN] histogram
constexpr size_t OFF_CUR = 1024 * 1024;              // int[NN] cursor -> row_end
constexpr size_t OFF_BS  = 1536 * 1024;              // int[512] block sums
constexpr size_t OFF_WB  = 1552 * 1024;              // bf16 weights (98304 elems)
constexpr size_t OFF_SRC = 2 * 1024 * 1024;          // int[NE]
constexpr size_t OFF_B0  = 6 * 1024 * 1024;          // bf16[100096*128]  xb / h2b
constexpr size_t OFF_B1  = OFF_B0 + 26 * 1024 * 1024; // aggb / Ub
constexpr size_t OFF_B2  = OFF_B1 + 26 * 1024 * 1024; // h1b / Vb

__device__ __forceinline__ unsigned short f2b(float f) {
    unsigned u = __builtin_bit_cast(unsigned, f);
    return (unsigned short)((u + 0x7FFFu + ((u >> 16) & 1u)) >> 16);
}
__device__ __forceinline__ float b2f(unsigned short h) {
    unsigned u = ((unsigned)h) << 16;
    return __builtin_bit_cast(float, u);
}

// ---------------- conversions ----------------
__global__ __launch_bounds__(256) void k_cvt(const float* __restrict__ in,
                                             unsigned short* __restrict__ outp,
                                             int n4) {
    int i = blockIdx.x * 256 + threadIdx.x;
    if (i >= n4) return;
    float4 v = *(const float4*)&in[(size_t)i * 4];
    ushort4 o;
    o.x = f2b(v.x); o.y = f2b(v.y); o.z = f2b(v.z); o.w = f2b(v.w);
    *(ushort4*)&outp[(size_t)i * 4] = o;
}

// concat-convert the 5 weight matrices into one bf16 blob
__global__ __launch_bounds__(256) void k_cvt_w(const float* __restrict__ W1l,
                                               const float* __restrict__ W1r,
                                               const float* __restrict__ W2l,
                                               const float* __restrict__ W2r,
                                               const float* __restrict__ Wm1,
                                               unsigned short* __restrict__ outp) {
    int i = blockIdx.x * 256 + threadIdx.x;   // 0..98303
    float v;
    if (i < 16384) v = W1l[i];
    else if (i < 32768) v = W1r[i - 16384];
    else if (i < 49152) v = W2l[i - 32768];
    else if (i < 65536) v = W2r[i - 49152];
    else v = Wm1[i - 65536];
    outp[i] = f2b(v);
}

// ---------------- CSR build ----------------
__global__ __launch_bounds__(256) void k_hist(const int* __restrict__ dst,
                                              int* __restrict__ cnt) {
    int e = blockIdx.x * 256 + threadIdx.x;
    if (e < NE) atomicAdd(&cnt[dst[e]], 1);
}

__global__ __launch_bounds__(256) void k_scan1(const int* __restrict__ cnt,
                                               int* __restrict__ bsum) {
    int i = blockIdx.x * 256 + threadIdx.x;
    int v = (i < NN) ? cnt[i] : 0;
    #pragma unroll
    for (int o = 1; o < 64; o <<= 1) v += __shfl_xor(v, o);
    __shared__ int wsum[4];
    if ((threadIdx.x & 63) == 0) wsum[threadIdx.x >> 6] = v;
    __syncthreads();
    if (threadIdx.x == 0) bsum[blockIdx.x] = wsum[0] + wsum[1] + wsum[2] + wsum[3];
}

__global__ __launch_bounds__(512) void k_scan2(int* __restrict__ bsum, int nb) {
    __shared__ int s[512];
    int t = threadIdx.x;
    int v = (t < nb) ? bsum[t] : 0;
    s[t] = v;
    __syncthreads();
    for (int o = 1; o < 512; o <<= 1) {
        int u = (t >= o) ? s[t - o] : 0;
        __syncthreads();
        s[t] += u;
        __syncthreads();
    }
    if (t < nb) bsum[t] = s[t] - v;   // exclusive
}

__global__ __launch_bounds__(256) void k_scan3(const int* __restrict__ cnt,
                                               const int* __restrict__ bsum,
                                               int* __restrict__ rs,
                                               int* __restrict__ cur) {
    __shared__ int s[256];
    int t = threadIdx.x;
    int i = blockIdx.x * 256 + t;
    int v = (i < NN) ? cnt[i] : 0;
    s[t] = v;
    __syncthreads();
    for (int o = 1; o < 256; o <<= 1) {
        int u = (t >= o) ? s[t - o] : 0;
        __syncthreads();
        s[t] += u;
        __syncthreads();
    }
    int ex = s[t] - v + bsum[blockIdx.x];
    if (i < NN) { rs[i] = ex; cur[i] = ex; }
    if (i == NN - 1) rs[NN] = ex + v;
}

__global__ __launch_bounds__(256) void k_scatter_idx(const int* __restrict__ src,
                                                     const int* __restrict__ dst,
                                                     int* __restrict__ cur,
                                                     int* __restrict__ srcs) {
    int e = blockIdx.x * 256 + threadIdx.x;
    if (e < NE) {
        int pos = atomicAdd(&cur[dst[e]], 1);
        srcs[pos] = src[e];
    }
}

// ---------------- gather-aggregate (mean), bf16 in/out ----------------
// 16 lanes per node, 8 elems (16B) per lane, dual accumulators
__global__ __launch_bounds__(256) void k_agg(const unsigned short* __restrict__ feat,
                                             const int* __restrict__ rs,
                                             const int* __restrict__ re,
                                             const int* __restrict__ srcs,
                                             unsigned short* __restrict__ aggb) {
    int t = blockIdx.x * 256 + threadIdx.x;
    int n = t >> 4, q = t & 15;
    if (n >= NN) return;
    int b = rs[n], e = re[n];
    float a0[8] = {}, a1[8] = {};
    int j = b;
    for (; j + 1 < e; j += 2) {
        int s0 = srcs[j], s1 = srcs[j + 1];
        u16x8 v0 = *(const u16x8*)&feat[(size_t)s0 * D + q * 8];
        u16x8 v1 = *(const u16x8*)&feat[(size_t)s1 * D + q * 8];
        #pragma unroll
        for (int i = 0; i < 8; ++i) a0[i] += b2f(v0[i]);
        #pragma unroll
        for (int i = 0; i < 8; ++i) a1[i] += b2f(v1[i]);
    }
    if (j < e) {
        int s0 = srcs[j];
        u16x8 v0 = *(const u16x8*)&feat[(size_t)s0 * D + q * 8];
        #pragma unroll
        for (int i = 0; i < 8; ++i) a0[i] += b2f(v0[i]);
    }
    float inv = 1.0f / fmaxf((float)(e - b), 1.0f);
    u16x8 o;
    #pragma unroll
    for (int i = 0; i < 8; ++i) o[i] = f2b((a0[i] + a1[i]) * inv);
    *(u16x8*)&aggb[(size_t)n * D + q * 8] = o;
}

// ---------------- MFMA SAGE conv: h = relu(agg@Wl^T + b + x@Wr^T), bf16 -----
// 256 thr = 4 waves; block = 128 rows; wave = 32 rows x 128 cols.
__global__ __launch_bounds__(256) void k_conv_mfma(const unsigned short* __restrict__ aggb,
                                                   const unsigned short* __restrict__ xb,
                                                   const unsigned short* __restrict__ Wlb,
                                                   const unsigned short* __restrict__ Wrb,
                                                   const float* __restrict__ bias,
                                                   unsigned short* __restrict__ hout) {
    const int tid = threadIdx.x;
    const int wv = tid >> 6, l = tid & 63;
    const int lrow = l & 15;
    const int lk   = (l >> 4) * 8;
    const int n0   = blockIdx.x * 128 + wv * 32;
    f32x4 acc[2][8] = {};

    #pragma unroll
    for (int p = 0; p < 2; ++p) {
        const unsigned short* A = p ? xb : aggb;
        const unsigned short* W = p ? Wrb : Wlb;
        #pragma unroll
        for (int ks = 0; ks < 4; ++ks) {
            const int k0 = ks * 32;
            bf16x8 af[2];
            #pragma unroll
            for (int mt = 0; mt < 2; ++mt) {
                int r = n0 + mt * 16 + lrow;
                if (r > NN - 1) r = NN - 1;
                af[mt] = *(const bf16x8*)&A[(size_t)r * D + k0 + lk];
            }
            #pragma unroll
            for (int nt = 0; nt < 8; ++nt) {
                bf16x8 bfr = *(const bf16x8*)&W[(size_t)(nt * 16 + lrow) * D + k0 + lk];
                acc[0][nt] = __builtin_amdgcn_mfma_f32_16x16x32_bf16(af[0], bfr, acc[0][nt], 0, 0, 0);
                acc[1][nt] = __builtin_amdgcn_mfma_f32_16x16x32_bf16(af[1], bfr, acc[1][nt], 0, 0, 0);
            }
        }
    }
    const int orow = (l >> 4) * 4;
    const int ocol = l & 15;
    #pragma unroll
    for (int nt = 0; nt < 8; ++nt) {
        float bb = bias[nt * 16 + ocol];
        #pragma unroll
        for (int mt = 0; mt < 2; ++mt) {
            #pragma unroll
            for (int j = 0; j < 4; ++j) {
                int r = n0 + mt * 16 + orow + j;
                if (r < NN)
                    hout[(size_t)r * D + nt * 16 + ocol] = f2b(fmaxf(acc[mt][nt][j] + bb, 0.0f));
            }
        }
    }
}

// ---------------- fused U/V: U = h2@Wm1[:, :128]^T + bm1 ; V = h2@Wm1[:, 128:]^T
// 512 thr = 8 waves; waves 0-3 -> U, 4-7 -> V; block = 128 rows.
__global__ __launch_bounds__(512) void k_linUV(const unsigned short* __restrict__ h2b,
                                               const unsigned short* __restrict__ Wm1b,
                                               const float* __restrict__ bm1,
                                               unsigned short* __restrict__ Ub,
                                               unsigned short* __restrict__ Vb) {
    const int tid = threadIdx.x;
    const int wv = tid >> 6, l = tid & 63;
    const int half = wv >> 2;        // 0: U, 1: V
    const int wm   = wv & 3;
    const int lrow = l & 15;
    const int lk   = (l >> 4) * 8;
    const int n0   = blockIdx.x * 128 + wm * 32;
    f32x4 acc[2][8] = {};

    #pragma unroll
    for (int ks = 0; ks < 4; ++ks) {
        const int k0 = ks * 32;
        bf16x8 af[2];
        #pragma unroll
        for (int mt = 0; mt < 2; ++mt) {
            int r = n0 + mt * 16 + lrow;
            if (r > NN - 1) r = NN - 1;
            af[mt] = *(const bf16x8*)&h2b[(size_t)r * D + k0 + lk];
        }
        #pragma unroll
        for (int nt = 0; nt < 8; ++nt) {
            bf16x8 bfr = *(const bf16x8*)&Wm1b[(size_t)(nt * 16 + lrow) * 256 + half * 128 + k0 + lk];
            acc[0][nt] = __builtin_amdgcn_mfma_f32_16x16x32_bf16(af[0], bfr, acc[0][nt], 0, 0, 0);
            acc[1][nt] = __builtin_amdgcn_mfma_f32_16x16x32_bf16(af[1], bfr, acc[1][nt], 0, 0, 0);
        }
    }
    unsigned short* O = half ? Vb : Ub;
    const int orow = (l >> 4) * 4;
    const int ocol = l & 15;
    #pragma unroll
    for (int nt = 0; nt < 8; ++nt) {
        float bb = half ? 0.0f : bm1[nt * 16 + ocol];
        #pragma unroll
        for (int mt = 0; mt < 2; ++mt) {
            #pragma unroll
            for (int j = 0; j < 4; ++j) {
                int r = n0 + mt * 16 + orow + j;
                if (r < NN)
                    O[(size_t)r * D + nt * 16 + ocol] = f2b(acc[mt][nt][j] + bb);
            }
        }
    }
}

// ---------------- edge finalize: sigmoid(wm2 . relu(U[s]+V[d]) + bm2) -------
__global__ __launch_bounds__(256) void k_edge_out(const unsigned short* __restrict__ Ub,
                                                  const unsigned short* __restrict__ Vb,
                                                  const int* __restrict__ src,
                                                  const int* __restrict__ dst,
                                                  const float* __restrict__ wm2,
                                                  const float* __restrict__ bm2,
                                                  float* __restrict__ out) {
    int t = blockIdx.x * 256 + threadIdx.x;
    int e = t >> 4, q = t & 15;
    if (e >= NE) return;
    int s = src[e], d = dst[e];
    u16x8 uu = *(const u16x8*)&Ub[(size_t)s * D + q * 8];
    u16x8 vv = *(const u16x8*)&Vb[(size_t)d * D + q * 8];
    float part = 0.0f;
    #pragma unroll
    for (int i = 0; i < 8; ++i) {
        float w = wm2[q * 8 + i];
        part += fmaxf(b2f(uu[i]) + b2f(vv[i]), 0.0f) * w;
    }
    #pragma unroll
    for (int off = 1; off < 16; off <<= 1) part += __shfl_xor(part, off);
    if (q == 0) out[e] = 1.0f / (1.0f + expf(-(part + bm2[0])));
}

extern "C" void kernel_launch(void* const* d_in, const int* in_sizes, int n_in,
                              void* d_out, int out_size, void* d_ws, size_t ws_size,
                              hipStream_t stream) {
    const float* x   = (const float*)d_in[0];
    const int*   ei  = (const int*)d_in[1];
    const int*   src = ei;
    const int*   dst = ei + NE;
    const float* W1l = (const float*)d_in[2];
    const float* b1l = (const float*)d_in[3];
    const float* W1r = (const float*)d_in[4];
    const float* W2l = (const float*)d_in[5];
    const float* b2l = (const float*)d_in[6];
    const float* W2r = (const float*)d_in[7];
    const float* Wm1 = (const float*)d_in[8];
    const float* bm1 = (const float*)d_in[9];
    const float* Wm2 = (const float*)d_in[10];
    const float* bm2 = (const float*)d_in[11];
    float* out = (float*)d_out;

    char* ws = (char*)d_ws;
    int* rs   = (int*)(ws + OFF_RS);
    int* cnt  = (int*)(ws + OFF_CNT);
    int* cur  = (int*)(ws + OFF_CUR);    // becomes row_end after scatter_idx
    int* bsum = (int*)(ws + OFF_BS);
    unsigned short* wb   = (unsigned short*)(ws + OFF_WB);
    int* srcs = (int*)(ws + OFF_SRC);
    unsigned short* B0 = (unsigned short*)(ws + OFF_B0);  // xb, later h2b
    unsigned short* B1 = (unsigned short*)(ws + OFF_B1);  // aggb, later Ub
    unsigned short* B2 = (unsigned short*)(ws + OFF_B2);  // h1b, later Vb

    unsigned short* W1lb = wb;
    unsigned short* W1rb = wb + 16384;
    unsigned short* W2lb = wb + 32768;
    unsigned short* W2rb = wb + 49152;
    unsigned short* Wm1b = wb + 65536;

    const int NB = 391;  // ceil(NN/256)

    hipMemsetAsync(cnt, 0, NN * sizeof(int), stream);
    k_cvt<<<(NN * D / 4 + 255) / 256, 256, 0, stream>>>(x, B0, NN * D / 4);
    k_cvt_w<<<384, 256, 0, stream>>>(W1l, W1r, W2l, W2r, Wm1, wb);
    k_hist<<<(NE + 255) / 256, 256, 0, stream>>>(dst, cnt);
    k_scan1<<<NB, 256, 0, stream>>>(cnt, bsum);
    k_scan2<<<1, 512, 0, stream>>>(bsum, NB);
    k_scan3<<<NB, 256, 0, stream>>>(cnt, bsum, rs, cur);
    k_scatter_idx<<<(NE + 255) / 256, 256, 0, stream>>>(src, dst, cur, srcs);

    k_agg<<<(NN * 16 + 255) / 256, 256, 0, stream>>>(B0, rs, cur, srcs, B1);
    k_conv_mfma<<<(NN + 127) / 128, 256, 0, stream>>>(B1, B0, W1lb, W1rb, b1l, B2);   // h1 -> B2
    k_agg<<<(NN * 16 + 255) / 256, 256, 0, stream>>>(B2, rs, cur, srcs, B1);
    k_conv_mfma<<<(NN + 127) / 128, 256, 0, stream>>>(B1, B2, W2lb, W2rb, b2l, B0);   // h2 -> B0
    k_linUV<<<(NN + 127) / 128, 512, 0, stream>>>(B0, Wm1b, bm1, B1, B2);             // U -> B1, V -> B2
    k_edge_out<<<(NE * 16 + 255) / 256, 256, 0, stream>>>(B1, B2, src, dst, Wm2, bm2, out);
}

// Round 4
// 366.051 us; speedup vs baseline: 9.6510x; 1.1180x over previous
//
#include <hip/hip_runtime.h>
#include <math.h>

#define NN 100000
#define NE 800000
#define D 128

typedef __attribute__((ext_vector_type(8))) short bf16x8;
typedef __attribute__((ext_vector_type(8))) unsigned short u16x8;
typedef __attribute__((ext_vector_type(4))) float f32x4;

// ---- workspace layout (bytes) ----
constexpr size_t OFF_RS  = 0;                         // int[NN+1]
constexpr size_t OFF_CNT = 512 * 1024;                // int[NN] histogram
constexpr size_t OFF_CUR = 1024 * 1024;               // int[NN] cursor -> row_end
constexpr size_t OFF_BS  = 1536 * 1024;               // int[512] block sums
constexpr size_t OFF_WB  = 1552 * 1024;               // bf16 weights (98304 elems)
constexpr size_t OFF_SRC = 2 * 1024 * 1024;           // int[NE]
constexpr size_t OFF_EID = 6 * 1024 * 1024;           // int[NE]
constexpr size_t OFF_B0  = 10 * 1024 * 1024;          // bf16[100096*128] xb -> Vb
constexpr size_t OFF_B1  = OFF_B0 + 26 * 1024 * 1024; // aggb
constexpr size_t OFF_B2  = OFF_B1 + 26 * 1024 * 1024; // h1b
constexpr size_t OFF_B3  = OFF_B2 + 26 * 1024 * 1024; // Ub

__device__ __forceinline__ unsigned short f2b(float f) {
    unsigned u = __builtin_bit_cast(unsigned, f);
    return (unsigned short)((u + 0x7FFFu + ((u >> 16) & 1u)) >> 16);
}
__device__ __forceinline__ float b2f(unsigned short h) {
    unsigned u = ((unsigned)h) << 16;
    return __builtin_bit_cast(float, u);
}

// ---------------- conversions ----------------
__global__ __launch_bounds__(256) void k_cvt(const float* __restrict__ in,
                                             unsigned short* __restrict__ outp,
                                             int n4) {
    int i = blockIdx.x * 256 + threadIdx.x;
    if (i >= n4) return;
    float4 v = *(const float4*)&in[(size_t)i * 4];
    ushort4 o;
    o.x = f2b(v.x); o.y = f2b(v.y); o.z = f2b(v.z); o.w = f2b(v.w);
    *(ushort4*)&outp[(size_t)i * 4] = o;
}

__global__ __launch_bounds__(256) void k_cvt_w(const float* __restrict__ W1l,
                                               const float* __restrict__ W1r,
                                               const float* __restrict__ W2l,
                                               const float* __restrict__ W2r,
                                               const float* __restrict__ Wm1,
                                               unsigned short* __restrict__ outp) {
    int i = blockIdx.x * 256 + threadIdx.x;   // 0..98303
    float v;
    if (i < 16384) v = W1l[i];
    else if (i < 32768) v = W1r[i - 16384];
    else if (i < 49152) v = W2l[i - 32768];
    else if (i < 65536) v = W2r[i - 49152];
    else v = Wm1[i - 65536];
    outp[i] = f2b(v);
}

// ---------------- CSR build ----------------
__global__ __launch_bounds__(256) void k_hist(const int* __restrict__ dst,
                                              int* __restrict__ cnt) {
    int e = blockIdx.x * 256 + threadIdx.x;
    if (e < NE) atomicAdd(&cnt[dst[e]], 1);
}

__global__ __launch_bounds__(256) void k_scan1(const int* __restrict__ cnt,
                                               int* __restrict__ bsum) {
    int i = blockIdx.x * 256 + threadIdx.x;
    int v = (i < NN) ? cnt[i] : 0;
    #pragma unroll
    for (int o = 1; o < 64; o <<= 1) v += __shfl_xor(v, o);
    __shared__ int wsum[4];
    if ((threadIdx.x & 63) == 0) wsum[threadIdx.x >> 6] = v;
    __syncthreads();
    if (threadIdx.x == 0) bsum[blockIdx.x] = wsum[0] + wsum[1] + wsum[2] + wsum[3];
}

__global__ __launch_bounds__(512) void k_scan2(int* __restrict__ bsum, int nb) {
    __shared__ int s[512];
    int t = threadIdx.x;
    int v = (t < nb) ? bsum[t] : 0;
    s[t] = v;
    __syncthreads();
    for (int o = 1; o < 512; o <<= 1) {
        int u = (t >= o) ? s[t - o] : 0;
        __syncthreads();
        s[t] += u;
        __syncthreads();
    }
    if (t < nb) bsum[t] = s[t] - v;   // exclusive
}

__global__ __launch_bounds__(256) void k_scan3(const int* __restrict__ cnt,
                                               const int* __restrict__ bsum,
                                               int* __restrict__ rs,
                                               int* __restrict__ cur) {
    __shared__ int s[256];
    int t = threadIdx.x;
    int i = blockIdx.x * 256 + t;
    int v = (i < NN) ? cnt[i] : 0;
    s[t] = v;
    __syncthreads();
    for (int o = 1; o < 256; o <<= 1) {
        int u = (t >= o) ? s[t - o] : 0;
        __syncthreads();
        s[t] += u;
        __syncthreads();
    }
    int ex = s[t] - v + bsum[blockIdx.x];
    if (i < NN) { rs[i] = ex; cur[i] = ex; }
    if (i == NN - 1) rs[NN] = ex + v;
}

__global__ __launch_bounds__(256) void k_scatter_idx(const int* __restrict__ src,
                                                     const int* __restrict__ dst,
                                                     int* __restrict__ cur,
                                                     int* __restrict__ srcs,
                                                     int* __restrict__ eids) {
    int e = blockIdx.x * 256 + threadIdx.x;
    if (e < NE) {
        int pos = atomicAdd(&cur[dst[e]], 1);
        srcs[pos] = src[e];
        eids[pos] = e;
    }
}

// ---------------- gather-aggregate (mean), bf16 in/out ----------------
__global__ __launch_bounds__(256) void k_agg(const unsigned short* __restrict__ feat,
                                             const int* __restrict__ rs,
                                             const int* __restrict__ re,
                                             const int* __restrict__ srcs,
                                             unsigned short* __restrict__ aggb) {
    int t = blockIdx.x * 256 + threadIdx.x;
    int n = t >> 4, q = t & 15;
    if (n >= NN) return;
    int b = rs[n], e = re[n];
    float a0[8] = {}, a1[8] = {};
    int j = b;
    for (; j + 1 < e; j += 2) {
        int s0 = srcs[j], s1 = srcs[j + 1];
        u16x8 v0 = *(const u16x8*)&feat[(size_t)s0 * D + q * 8];
        u16x8 v1 = *(const u16x8*)&feat[(size_t)s1 * D + q * 8];
        #pragma unroll
        for (int i = 0; i < 8; ++i) a0[i] += b2f(v0[i]);
        #pragma unroll
        for (int i = 0; i < 8; ++i) a1[i] += b2f(v1[i]);
    }
    if (j < e) {
        int s0 = srcs[j];
        u16x8 v0 = *(const u16x8*)&feat[(size_t)s0 * D + q * 8];
        #pragma unroll
        for (int i = 0; i < 8; ++i) a0[i] += b2f(v0[i]);
    }
    float inv = 1.0f / fmaxf((float)(e - b), 1.0f);
    u16x8 o;
    #pragma unroll
    for (int i = 0; i < 8; ++i) o[i] = f2b((a0[i] + a1[i]) * inv);
    *(u16x8*)&aggb[(size_t)n * D + q * 8] = o;
}

// ---------------- MFMA SAGE conv: h = relu(agg@Wl^T + b + x@Wr^T) -----------
// 4 waves/block; wave = 32 rows x 128 cols; LDS-staged coalesced stores.
__global__ __launch_bounds__(256) void k_conv_mfma(const unsigned short* __restrict__ aggb,
                                                   const unsigned short* __restrict__ xb,
                                                   const unsigned short* __restrict__ Wlb,
                                                   const unsigned short* __restrict__ Wrb,
                                                   const float* __restrict__ bias,
                                                   unsigned short* __restrict__ hout) {
    __shared__ unsigned short st[4][32 * 132];
    const int tid = threadIdx.x;
    const int wv = tid >> 6, l = tid & 63;
    unsigned short* S = &st[wv][0];
    const int lrow = l & 15;
    const int lk   = (l >> 4) * 8;
    const int n0   = blockIdx.x * 128 + wv * 32;
    f32x4 acc[2][8] = {};

    #pragma unroll
    for (int p = 0; p < 2; ++p) {
        const unsigned short* A = p ? xb : aggb;
        const unsigned short* W = p ? Wrb : Wlb;
        #pragma unroll
        for (int ks = 0; ks < 4; ++ks) {
            const int k0 = ks * 32;
            bf16x8 af[2];
            #pragma unroll
            for (int mt = 0; mt < 2; ++mt) {
                int r = n0 + mt * 16 + lrow;
                if (r > NN - 1) r = NN - 1;
                af[mt] = *(const bf16x8*)&A[(size_t)r * D + k0 + lk];
            }
            #pragma unroll
            for (int nt = 0; nt < 8; ++nt) {
                bf16x8 bfr = *(const bf16x8*)&W[(size_t)(nt * 16 + lrow) * D + k0 + lk];
                acc[0][nt] = __builtin_amdgcn_mfma_f32_16x16x32_bf16(af[0], bfr, acc[0][nt], 0, 0, 0);
                acc[1][nt] = __builtin_amdgcn_mfma_f32_16x16x32_bf16(af[1], bfr, acc[1][nt], 0, 0, 0);
            }
        }
    }
    // bias + relu + cvt -> LDS stage
    const int orow = (l >> 4) * 4;
    const int ocol = l & 15;
    #pragma unroll
    for (int nt = 0; nt < 8; ++nt) {
        float bb = bias[nt * 16 + ocol];
        #pragma unroll
        for (int mt = 0; mt < 2; ++mt) {
            #pragma unroll
            for (int j = 0; j < 4; ++j)
                S[(mt * 16 + orow + j) * 132 + nt * 16 + ocol] =
                    f2b(fmaxf(acc[mt][nt][j] + bb, 0.0f));
        }
    }
    __syncthreads();
    // coalesced store: 1KB per instruction
    #pragma unroll
    for (int i = 0; i < 8; ++i) {
        int r  = i * 4 + (l >> 4);
        int gr = n0 + r;
        u16x8 v = *(const u16x8*)&S[r * 132 + (l & 15) * 8];
        if (gr < NN) *(u16x8*)&hout[(size_t)gr * D + (l & 15) * 8] = v;
    }
}

// ---------------- fused conv2 + U/V ----------------
// phase1: h2 tile = relu(agg@W2l^T+b2l+h1@W2r^T) -> LDS (never global)
// phase2: U = h2@Wm1[:,:128]^T + bm1 ; V = h2@Wm1[:,128:]^T, coalesced stores
__global__ __launch_bounds__(256) void k_conv2uv(const unsigned short* __restrict__ aggb,
                                                 const unsigned short* __restrict__ h1b,
                                                 const unsigned short* __restrict__ Wlb,
                                                 const unsigned short* __restrict__ Wrb,
                                                 const float* __restrict__ bias,
                                                 const unsigned short* __restrict__ Wm1b,
                                                 const float* __restrict__ bm1,
                                                 unsigned short* __restrict__ Ub,
                                                 unsigned short* __restrict__ Vb) {
    __shared__ unsigned short st[4][32 * 132];
    const int tid = threadIdx.x;
    const int wv = tid >> 6, l = tid & 63;
    unsigned short* S = &st[wv][0];
    const int lrow = l & 15;
    const int lk   = (l >> 4) * 8;
    const int n0   = blockIdx.x * 128 + wv * 32;
    const int orow = (l >> 4) * 4;
    const int ocol = l & 15;

    {   // ---- phase 1: h2 tile ----
        f32x4 acc[2][8] = {};
        #pragma unroll
        for (int p = 0; p < 2; ++p) {
            const unsigned short* A = p ? h1b : aggb;
            const unsigned short* W = p ? Wrb : Wlb;
            #pragma unroll
            for (int ks = 0; ks < 4; ++ks) {
                const int k0 = ks * 32;
                bf16x8 af[2];
                #pragma unroll
                for (int mt = 0; mt < 2; ++mt) {
                    int r = n0 + mt * 16 + lrow;
                    if (r > NN - 1) r = NN - 1;
                    af[mt] = *(const bf16x8*)&A[(size_t)r * D + k0 + lk];
                }
                #pragma unroll
                for (int nt = 0; nt < 8; ++nt) {
                    bf16x8 bfr = *(const bf16x8*)&W[(size_t)(nt * 16 + lrow) * D + k0 + lk];
                    acc[0][nt] = __builtin_amdgcn_mfma_f32_16x16x32_bf16(af[0], bfr, acc[0][nt], 0, 0, 0);
                    acc[1][nt] = __builtin_amdgcn_mfma_f32_16x16x32_bf16(af[1], bfr, acc[1][nt], 0, 0, 0);
                }
            }
        }
        #pragma unroll
        for (int nt = 0; nt < 8; ++nt) {
            float bb = bias[nt * 16 + ocol];
            #pragma unroll
            for (int mt = 0; mt < 2; ++mt) {
                #pragma unroll
                for (int j = 0; j < 4; ++j)
                    S[(mt * 16 + orow + j) * 132 + nt * 16 + ocol] =
                        f2b(fmaxf(acc[mt][nt][j] + bb, 0.0f));
            }
        }
    }
    __syncthreads();
    // ---- read h2 A-fragments back from LDS ----
    bf16x8 af2[2][4];
    #pragma unroll
    for (int mt = 0; mt < 2; ++mt)
        #pragma unroll
        for (int ks = 0; ks < 4; ++ks)
            af2[mt][ks] = *(const bf16x8*)&S[(mt * 16 + lrow) * 132 + ks * 32 + lk];
    __syncthreads();

    // ---- U then V (reuse acc + LDS stage) ----
    #pragma unroll
    for (int half = 0; half < 2; ++half) {
        f32x4 acc[2][8] = {};
        #pragma unroll
        for (int ks = 0; ks < 4; ++ks) {
            #pragma unroll
            for (int nt = 0; nt < 8; ++nt) {
                bf16x8 bfr = *(const bf16x8*)&Wm1b[(size_t)(nt * 16 + lrow) * 256 + half * 128 + ks * 32 + lk];
                acc[0][nt] = __builtin_amdgcn_mfma_f32_16x16x32_bf16(af2[0][ks], bfr, acc[0][nt], 0, 0, 0);
                acc[1][nt] = __builtin_amdgcn_mfma_f32_16x16x32_bf16(af2[1][ks], bfr, acc[1][nt], 0, 0, 0);
            }
        }
        __syncthreads();
        #pragma unroll
        for (int nt = 0; nt < 8; ++nt) {
            float bb = half ? 0.0f : bm1[nt * 16 + ocol];
            #pragma unroll
            for (int mt = 0; mt < 2; ++mt) {
                #pragma unroll
                for (int j = 0; j < 4; ++j)
                    S[(mt * 16 + orow + j) * 132 + nt * 16 + ocol] = f2b(acc[mt][nt][j] + bb);
            }
        }
        __syncthreads();
        unsigned short* O = half ? Vb : Ub;
        #pragma unroll
        for (int i = 0; i < 8; ++i) {
            int r  = i * 4 + (l >> 4);
            int gr = n0 + r;
            u16x8 v = *(const u16x8*)&S[r * 132 + (l & 15) * 8];
            if (gr < NN) *(u16x8*)&O[(size_t)gr * D + (l & 15) * 8] = v;
        }
    }
}

// ---------------- edge finalize, dst-grouped: V[d] amortized ----------------
__global__ __launch_bounds__(256) void k_edge2(const unsigned short* __restrict__ Ub,
                                               const unsigned short* __restrict__ Vb,
                                               const int* __restrict__ rs,
                                               const int* __restrict__ re,
                                               const int* __restrict__ srcs,
                                               const int* __restrict__ eids,
                                               const float* __restrict__ wm2,
                                               const float* __restrict__ bm2,
                                               float* __restrict__ out) {
    int t = blockIdx.x * 256 + threadIdx.x;
    int g = t >> 4, q = t & 15;
    if (g >= NN) return;
    int b = rs[g], e = re[g];
    if (b == e) return;
    u16x8 vv = *(const u16x8*)&Vb[(size_t)g * D + q * 8];
    float vf[8], wf[8];
    #pragma unroll
    for (int i = 0; i < 8; ++i) vf[i] = b2f(vv[i]);
    float4 w0 = *(const float4*)&wm2[q * 8];
    float4 w1 = *(const float4*)&wm2[q * 8 + 4];
    wf[0] = w0.x; wf[1] = w0.y; wf[2] = w0.z; wf[3] = w0.w;
    wf[4] = w1.x; wf[5] = w1.y; wf[6] = w1.z; wf[7] = w1.w;
    const float bb = bm2[0];

    int j = b;
    for (; j + 1 < e; j += 2) {
        int s0 = srcs[j], s1 = srcs[j + 1];
        int e0 = eids[j], e1 = eids[j + 1];
        u16x8 u0 = *(const u16x8*)&Ub[(size_t)s0 * D + q * 8];
        u16x8 u1 = *(const u16x8*)&Ub[(size_t)s1 * D + q * 8];
        float p0 = 0.f, p1 = 0.f;
        #pragma unroll
        for (int i = 0; i < 8; ++i) {
            p0 += fmaxf(b2f(u0[i]) + vf[i], 0.0f) * wf[i];
            p1 += fmaxf(b2f(u1[i]) + vf[i], 0.0f) * wf[i];
        }
        #pragma unroll
        for (int off = 1; off < 16; off <<= 1) {
            p0 += __shfl_xor(p0, off);
            p1 += __shfl_xor(p1, off);
        }
        if (q == 0) {
            out[e0] = 1.0f / (1.0f + expf(-(p0 + bb)));
            out[e1] = 1.0f / (1.0f + expf(-(p1 + bb)));
        }
    }
    if (j < e) {
        int s0 = srcs[j], e0 = eids[j];
        u16x8 u0 = *(const u16x8*)&Ub[(size_t)s0 * D + q * 8];
        float p0 = 0.f;
        #pragma unroll
        for (int i = 0; i < 8; ++i) p0 += fmaxf(b2f(u0[i]) + vf[i], 0.0f) * wf[i];
        #pragma unroll
        for (int off = 1; off < 16; off <<= 1) p0 += __shfl_xor(p0, off);
        if (q == 0) out[e0] = 1.0f / (1.0f + expf(-(p0 + bb)));
    }
}

extern "C" void kernel_launch(void* const* d_in, const int* in_sizes, int n_in,
                              void* d_out, int out_size, void* d_ws, size_t ws_size,
                              hipStream_t stream) {
    const float* x   = (const float*)d_in[0];
    const int*   ei  = (const int*)d_in[1];
    const int*   src = ei;
    const int*   dst = ei + NE;
    const float* W1l = (const float*)d_in[2];
    const float* b1l = (const float*)d_in[3];
    const float* W1r = (const float*)d_in[4];
    const float* W2l = (const float*)d_in[5];
    const float* b2l = (const float*)d_in[6];
    const float* W2r = (const float*)d_in[7];
    const float* Wm1 = (const float*)d_in[8];
    const float* bm1 = (const float*)d_in[9];
    const float* Wm2 = (const float*)d_in[10];
    const float* bm2 = (const float*)d_in[11];
    float* out = (float*)d_out;

    char* ws = (char*)d_ws;
    int* rs   = (int*)(ws + OFF_RS);
    int* cnt  = (int*)(ws + OFF_CNT);
    int* cur  = (int*)(ws + OFF_CUR);    // row_end after scatter_idx
    int* bsum = (int*)(ws + OFF_BS);
    unsigned short* wb = (unsigned short*)(ws + OFF_WB);
    int* srcs = (int*)(ws + OFF_SRC);
    int* eids = (int*)(ws + OFF_EID);
    unsigned short* B0 = (unsigned short*)(ws + OFF_B0);  // xb, later Vb
    unsigned short* B1 = (unsigned short*)(ws + OFF_B1);  // aggb
    unsigned short* B2 = (unsigned short*)(ws + OFF_B2);  // h1b
    unsigned short* B3 = (unsigned short*)(ws + OFF_B3);  // Ub

    unsigned short* W1lb = wb;
    unsigned short* W1rb = wb + 16384;
    unsigned short* W2lb = wb + 32768;
    unsigned short* W2rb = wb + 49152;
    unsigned short* Wm1b = wb + 65536;

    const int NB = 391;  // ceil(NN/256)

    hipMemsetAsync(cnt, 0, NN * sizeof(int), stream);
    k_cvt<<<(NN * D / 4 + 255) / 256, 256, 0, stream>>>(x, B0, NN * D / 4);
    k_cvt_w<<<384, 256, 0, stream>>>(W1l, W1r, W2l, W2r, Wm1, wb);
    k_hist<<<(NE + 255) / 256, 256, 0, stream>>>(dst, cnt);
    k_scan1<<<NB, 256, 0, stream>>>(cnt, bsum);
    k_scan2<<<1, 512, 0, stream>>>(bsum, NB);
    k_scan3<<<NB, 256, 0, stream>>>(cnt, bsum, rs, cur);
    k_scatter_idx<<<(NE + 255) / 256, 256, 0, stream>>>(src, dst, cur, srcs, eids);

    k_agg<<<(NN * 16 + 255) / 256, 256, 0, stream>>>(B0, rs, cur, srcs, B1);
    k_conv_mfma<<<(NN + 127) / 128, 256, 0, stream>>>(B1, B0, W1lb, W1rb, b1l, B2);     // h1 -> B2
    k_agg<<<(NN * 16 + 255) / 256, 256, 0, stream>>>(B2, rs, cur, srcs, B1);
    k_conv2uv<<<(NN + 127) / 128, 256, 0, stream>>>(B1, B2, W2lb, W2rb, b2l,
                                                    Wm1b, bm1, B3, B0);                  // U -> B3, V -> B0
    k_edge2<<<(NN * 16 + 255) / 256, 256, 0, stream>>>(B3, B0, rs, cur, srcs, eids,
                                                       Wm2, bm2, out);
}

// Round 5
// 353.533 us; speedup vs baseline: 9.9928x; 1.0354x over previous
//
#include <hip/hip_runtime.h>
#include <math.h>

#define NN 100000
#define NE 800000
#define D 128

typedef __attribute__((ext_vector_type(8))) short bf16x8;
typedef __attribute__((ext_vector_type(8))) unsigned short u16x8;
typedef __attribute__((ext_vector_type(4))) float f32x4;

// ---- workspace layout (bytes) ----
constexpr size_t OFF_RS  = 0;                         // int[NN+1]
constexpr size_t OFF_CNT = 512 * 1024;                // int[NN] histogram
constexpr size_t OFF_CUR = 1024 * 1024;               // int[NN] cursor -> row_end
constexpr size_t OFF_BS  = 1536 * 1024;               // int[512] block sums
constexpr size_t OFF_WB  = 1552 * 1024;               // bf16 weights (98304 elems)
constexpr size_t OFF_SRC = 2 * 1024 * 1024;           // int[NE]
constexpr size_t OFF_EID = 6 * 1024 * 1024;           // int[NE]
constexpr size_t OFF_B0  = 10 * 1024 * 1024;          // bf16[100096*128] xb -> Vb
constexpr size_t OFF_B1  = OFF_B0 + 26 * 1024 * 1024; // aggb
constexpr size_t OFF_B2  = OFF_B1 + 26 * 1024 * 1024; // h1b
constexpr size_t OFF_B3  = OFF_B2 + 26 * 1024 * 1024; // Ub

__device__ __forceinline__ unsigned short f2b(float f) {
    unsigned u = __builtin_bit_cast(unsigned, f);
    return (unsigned short)((u + 0x7FFFu + ((u >> 16) & 1u)) >> 16);
}
__device__ __forceinline__ float b2f(unsigned short h) {
    unsigned u = ((unsigned)h) << 16;
    return __builtin_bit_cast(float, u);
}

// ---------------- conversions ----------------
__global__ __launch_bounds__(256) void k_cvt(const float* __restrict__ in,
                                             unsigned short* __restrict__ outp,
                                             int n4) {
    int i = blockIdx.x * 256 + threadIdx.x;
    if (i >= n4) return;
    float4 v = *(const float4*)&in[(size_t)i * 4];
    ushort4 o;
    o.x = f2b(v.x); o.y = f2b(v.y); o.z = f2b(v.z); o.w = f2b(v.w);
    *(ushort4*)&outp[(size_t)i * 4] = o;
}

__global__ __launch_bounds__(256) void k_cvt_w(const float* __restrict__ W1l,
                                               const float* __restrict__ W1r,
                                               const float* __restrict__ W2l,
                                               const float* __restrict__ W2r,
                                               const float* __restrict__ Wm1,
                                               unsigned short* __restrict__ outp) {
    int i = blockIdx.x * 256 + threadIdx.x;   // 0..98303
    float v;
    if (i < 16384) v = W1l[i];
    else if (i < 32768) v = W1r[i - 16384];
    else if (i < 49152) v = W2l[i - 32768];
    else if (i < 65536) v = W2r[i - 49152];
    else v = Wm1[i - 65536];
    outp[i] = f2b(v);
}

// ---------------- CSR build ----------------
__global__ __launch_bounds__(256) void k_hist(const int* __restrict__ dst,
                                              int* __restrict__ cnt) {
    int e = blockIdx.x * 256 + threadIdx.x;
    if (e < NE) atomicAdd(&cnt[dst[e]], 1);
}

__global__ __launch_bounds__(256) void k_scan1(const int* __restrict__ cnt,
                                               int* __restrict__ bsum) {
    int i = blockIdx.x * 256 + threadIdx.x;
    int v = (i < NN) ? cnt[i] : 0;
    #pragma unroll
    for (int o = 1; o < 64; o <<= 1) v += __shfl_xor(v, o);
    __shared__ int wsum[4];
    if ((threadIdx.x & 63) == 0) wsum[threadIdx.x >> 6] = v;
    __syncthreads();
    if (threadIdx.x == 0) bsum[blockIdx.x] = wsum[0] + wsum[1] + wsum[2] + wsum[3];
}

__global__ __launch_bounds__(512) void k_scan2(int* __restrict__ bsum, int nb) {
    __shared__ int s[512];
    int t = threadIdx.x;
    int v = (t < nb) ? bsum[t] : 0;
    s[t] = v;
    __syncthreads();
    for (int o = 1; o < 512; o <<= 1) {
        int u = (t >= o) ? s[t - o] : 0;
        __syncthreads();
        s[t] += u;
        __syncthreads();
    }
    if (t < nb) bsum[t] = s[t] - v;   // exclusive
}

__global__ __launch_bounds__(256) void k_scan3(const int* __restrict__ cnt,
                                               const int* __restrict__ bsum,
                                               int* __restrict__ rs,
                                               int* __restrict__ cur) {
    __shared__ int s[256];
    int t = threadIdx.x;
    int i = blockIdx.x * 256 + t;
    int v = (i < NN) ? cnt[i] : 0;
    s[t] = v;
    __syncthreads();
    for (int o = 1; o < 256; o <<= 1) {
        int u = (t >= o) ? s[t - o] : 0;
        __syncthreads();
        s[t] += u;
        __syncthreads();
    }
    int ex = s[t] - v + bsum[blockIdx.x];
    if (i < NN) { rs[i] = ex; cur[i] = ex; }
    if (i == NN - 1) rs[NN] = ex + v;
}

__global__ __launch_bounds__(256) void k_scatter_idx(const int* __restrict__ src,
                                                     const int* __restrict__ dst,
                                                     int* __restrict__ cur,
                                                     int* __restrict__ srcs,
                                                     int* __restrict__ eids) {
    int e = blockIdx.x * 256 + threadIdx.x;
    if (e < NE) {
        int pos = atomicAdd(&cur[dst[e]], 1);
        srcs[pos] = src[e];
        eids[pos] = e;
    }
}

// ---------------- gather-aggregate (mean), bf16 in/out, 4-unrolled ---------
__global__ __launch_bounds__(256) void k_agg(const unsigned short* __restrict__ feat,
                                             const int* __restrict__ rs,
                                             const int* __restrict__ re,
                                             const int* __restrict__ srcs,
                                             unsigned short* __restrict__ aggb) {
    int t = blockIdx.x * 256 + threadIdx.x;
    int n = t >> 4, q = t & 15;
    if (n >= NN) return;
    int b = rs[n], e = re[n];
    float a0[8] = {}, a1[8] = {}, a2[8] = {}, a3[8] = {};
    int j = b;
    for (; j + 3 < e; j += 4) {
        int s0 = srcs[j], s1 = srcs[j + 1], s2 = srcs[j + 2], s3 = srcs[j + 3];
        u16x8 v0 = *(const u16x8*)&feat[(size_t)s0 * D + q * 8];
        u16x8 v1 = *(const u16x8*)&feat[(size_t)s1 * D + q * 8];
        u16x8 v2 = *(const u16x8*)&feat[(size_t)s2 * D + q * 8];
        u16x8 v3 = *(const u16x8*)&feat[(size_t)s3 * D + q * 8];
        #pragma unroll
        for (int i = 0; i < 8; ++i) a0[i] += b2f(v0[i]);
        #pragma unroll
        for (int i = 0; i < 8; ++i) a1[i] += b2f(v1[i]);
        #pragma unroll
        for (int i = 0; i < 8; ++i) a2[i] += b2f(v2[i]);
        #pragma unroll
        for (int i = 0; i < 8; ++i) a3[i] += b2f(v3[i]);
    }
    for (; j < e; ++j) {
        int s0 = srcs[j];
        u16x8 v0 = *(const u16x8*)&feat[(size_t)s0 * D + q * 8];
        #pragma unroll
        for (int i = 0; i < 8; ++i) a0[i] += b2f(v0[i]);
    }
    float inv = 1.0f / fmaxf((float)(e - b), 1.0f);
    u16x8 o;
    #pragma unroll
    for (int i = 0; i < 8; ++i) o[i] = f2b((a0[i] + a1[i] + a2[i] + a3[i]) * inv);
    *(u16x8*)&aggb[(size_t)n * D + q * 8] = o;
}

// ---------------- MFMA SAGE conv: h = relu(agg@Wl^T + b + x@Wr^T) -----------
// Block = 32 rows (NN%32==0), 4 waves each owning 32 cols. Weights-stationary:
// B-fragments preloaded to registers once ([Wl|Wr] as one K=256 GEMM).
__global__ __launch_bounds__(256) void k_conv_mfma(const unsigned short* __restrict__ aggb,
                                                   const unsigned short* __restrict__ xb,
                                                   const unsigned short* __restrict__ Wlb,
                                                   const unsigned short* __restrict__ Wrb,
                                                   const float* __restrict__ bias,
                                                   unsigned short* __restrict__ hout) {
    __shared__ unsigned short st[32 * 136];
    const int tid = threadIdx.x;
    const int wc = tid >> 6, l = tid & 63;
    const int lrow = l & 15;
    const int lk   = (l >> 4) * 8;
    const int n0   = blockIdx.x * 32;

    bf16x8 bf[2][4][2];
    #pragma unroll
    for (int p = 0; p < 2; ++p) {
        const unsigned short* W = p ? Wrb : Wlb;
        #pragma unroll
        for (int ks = 0; ks < 4; ++ks)
            #pragma unroll
            for (int nt = 0; nt < 2; ++nt)
                bf[p][ks][nt] = *(const bf16x8*)&W[(size_t)(wc * 32 + nt * 16 + lrow) * D + ks * 32 + lk];
    }
    f32x4 acc[2][2] = {};
    #pragma unroll
    for (int p = 0; p < 2; ++p) {
        const unsigned short* A = p ? xb : aggb;
        #pragma unroll
        for (int ks = 0; ks < 4; ++ks) {
            bf16x8 af0 = *(const bf16x8*)&A[(size_t)(n0 + lrow) * D + ks * 32 + lk];
            bf16x8 af1 = *(const bf16x8*)&A[(size_t)(n0 + 16 + lrow) * D + ks * 32 + lk];
            #pragma unroll
            for (int nt = 0; nt < 2; ++nt) {
                acc[0][nt] = __builtin_amdgcn_mfma_f32_16x16x32_bf16(af0, bf[p][ks][nt], acc[0][nt], 0, 0, 0);
                acc[1][nt] = __builtin_amdgcn_mfma_f32_16x16x32_bf16(af1, bf[p][ks][nt], acc[1][nt], 0, 0, 0);
            }
        }
    }
    const int orow = (l >> 4) * 4;
    const int ocol = l & 15;
    #pragma unroll
    for (int nt = 0; nt < 2; ++nt) {
        float bb = bias[wc * 32 + nt * 16 + ocol];
        #pragma unroll
        for (int mt = 0; mt < 2; ++mt)
            #pragma unroll
            for (int j = 0; j < 4; ++j)
                st[(mt * 16 + orow + j) * 136 + wc * 32 + nt * 16 + ocol] =
                    f2b(fmaxf(acc[mt][nt][j] + bb, 0.0f));
    }
    __syncthreads();
    // coalesced store: 2 iters x 256 thr x 16B
    #pragma unroll
    for (int it = 0; it < 2; ++it) {
        int r = it * 16 + (tid >> 4);
        int c = (tid & 15) * 8;
        u16x8 v = *(const u16x8*)&st[r * 136 + c];
        *(u16x8*)&hout[(size_t)(n0 + r) * D + c] = v;
    }
}

// ---------------- fused conv2 + U/V, weights-stationary ----------------
__global__ __launch_bounds__(256) void k_conv2uv(const unsigned short* __restrict__ aggb,
                                                 const unsigned short* __restrict__ h1b,
                                                 const unsigned short* __restrict__ Wlb,
                                                 const unsigned short* __restrict__ Wrb,
                                                 const float* __restrict__ bias,
                                                 const unsigned short* __restrict__ Wm1b,
                                                 const float* __restrict__ bm1,
                                                 unsigned short* __restrict__ Ub,
                                                 unsigned short* __restrict__ Vb) {
    __shared__ unsigned short st[32 * 136];
    const int tid = threadIdx.x;
    const int wc = tid >> 6, l = tid & 63;
    const int lrow = l & 15;
    const int lk   = (l >> 4) * 8;
    const int n0   = blockIdx.x * 32;
    const int orow = (l >> 4) * 4;
    const int ocol = l & 15;

    {   // ---- phase 1: h2 tile -> LDS ----
        bf16x8 bf[2][4][2];
        #pragma unroll
        for (int p = 0; p < 2; ++p) {
            const unsigned short* W = p ? Wrb : Wlb;
            #pragma unroll
            for (int ks = 0; ks < 4; ++ks)
                #pragma unroll
                for (int nt = 0; nt < 2; ++nt)
                    bf[p][ks][nt] = *(const bf16x8*)&W[(size_t)(wc * 32 + nt * 16 + lrow) * D + ks * 32 + lk];
        }
        f32x4 acc[2][2] = {};
        #pragma unroll
        for (int p = 0; p < 2; ++p) {
            const unsigned short* A = p ? h1b : aggb;
            #pragma unroll
            for (int ks = 0; ks < 4; ++ks) {
                bf16x8 af0 = *(const bf16x8*)&A[(size_t)(n0 + lrow) * D + ks * 32 + lk];
                bf16x8 af1 = *(const bf16x8*)&A[(size_t)(n0 + 16 + lrow) * D + ks * 32 + lk];
                #pragma unroll
                for (int nt = 0; nt < 2; ++nt) {
                    acc[0][nt] = __builtin_amdgcn_mfma_f32_16x16x32_bf16(af0, bf[p][ks][nt], acc[0][nt], 0, 0, 0);
                    acc[1][nt] = __builtin_amdgcn_mfma_f32_16x16x32_bf16(af1, bf[p][ks][nt], acc[1][nt], 0, 0, 0);
                }
            }
        }
        #pragma unroll
        for (int nt = 0; nt < 2; ++nt) {
            float bb = bias[wc * 32 + nt * 16 + ocol];
            #pragma unroll
            for (int mt = 0; mt < 2; ++mt)
                #pragma unroll
                for (int j = 0; j < 4; ++j)
                    st[(mt * 16 + orow + j) * 136 + wc * 32 + nt * 16 + ocol] =
                        f2b(fmaxf(acc[mt][nt][j] + bb, 0.0f));
        }
    }
    __syncthreads();
    // ---- h2 A-fragments from LDS (full K=128) ----
    bf16x8 af2[2][4];
    #pragma unroll
    for (int mt = 0; mt < 2; ++mt)
        #pragma unroll
        for (int ks = 0; ks < 4; ++ks)
            af2[mt][ks] = *(const bf16x8*)&st[(mt * 16 + lrow) * 136 + ks * 32 + lk];

    // ---- U and V interleaved (weights preloaded) ----
    bf16x8 bu[4][2], bv[4][2];
    #pragma unroll
    for (int ks = 0; ks < 4; ++ks)
        #pragma unroll
        for (int nt = 0; nt < 2; ++nt) {
            bu[ks][nt] = *(const bf16x8*)&Wm1b[(size_t)(wc * 32 + nt * 16 + lrow) * 256 + ks * 32 + lk];
            bv[ks][nt] = *(const bf16x8*)&Wm1b[(size_t)(wc * 32 + nt * 16 + lrow) * 256 + 128 + ks * 32 + lk];
        }
    f32x4 aU[2][2] = {}, aV[2][2] = {};
    #pragma unroll
    for (int ks = 0; ks < 4; ++ks)
        #pragma unroll
        for (int nt = 0; nt < 2; ++nt)
            #pragma unroll
            for (int mt = 0; mt < 2; ++mt) {
                aU[mt][nt] = __builtin_amdgcn_mfma_f32_16x16x32_bf16(af2[mt][ks], bu[ks][nt], aU[mt][nt], 0, 0, 0);
                aV[mt][nt] = __builtin_amdgcn_mfma_f32_16x16x32_bf16(af2[mt][ks], bv[ks][nt], aV[mt][nt], 0, 0, 0);
            }
    __syncthreads();
    // ---- stage + store U ----
    #pragma unroll
    for (int nt = 0; nt < 2; ++nt) {
        float bb = bm1[wc * 32 + nt * 16 + ocol];
        #pragma unroll
        for (int mt = 0; mt < 2; ++mt)
            #pragma unroll
            for (int j = 0; j < 4; ++j)
                st[(mt * 16 + orow + j) * 136 + wc * 32 + nt * 16 + ocol] = f2b(aU[mt][nt][j] + bb);
    }
    __syncthreads();
    #pragma unroll
    for (int it = 0; it < 2; ++it) {
        int r = it * 16 + (tid >> 4);
        int c = (tid & 15) * 8;
        u16x8 v = *(const u16x8*)&st[r * 136 + c];
        *(u16x8*)&Ub[(size_t)(n0 + r) * D + c] = v;
    }
    __syncthreads();
    // ---- stage + store V ----
    #pragma unroll
    for (int nt = 0; nt < 2; ++nt) {
        #pragma unroll
        for (int mt = 0; mt < 2; ++mt)
            #pragma unroll
            for (int j = 0; j < 4; ++j)
                st[(mt * 16 + orow + j) * 136 + wc * 32 + nt * 16 + ocol] = f2b(aV[mt][nt][j]);
    }
    __syncthreads();
    #pragma unroll
    for (int it = 0; it < 2; ++it) {
        int r = it * 16 + (tid >> 4);
        int c = (tid & 15) * 8;
        u16x8 v = *(const u16x8*)&st[r * 136 + c];
        *(u16x8*)&Vb[(size_t)(n0 + r) * D + c] = v;
    }
}

// ---------------- edge finalize, dst-grouped: V[d] amortized ----------------
__global__ __launch_bounds__(256) void k_edge2(const unsigned short* __restrict__ Ub,
                                               const unsigned short* __restrict__ Vb,
                                               const int* __restrict__ rs,
                                               const int* __restrict__ re,
                                               const int* __restrict__ srcs,
                                               const int* __restrict__ eids,
                                               const float* __restrict__ wm2,
                                               const float* __restrict__ bm2,
                                               float* __restrict__ out) {
    int t = blockIdx.x * 256 + threadIdx.x;
    int g = t >> 4, q = t & 15;
    if (g >= NN) return;
    int b = rs[g], e = re[g];
    if (b == e) return;
    u16x8 vv = *(const u16x8*)&Vb[(size_t)g * D + q * 8];
    float vf[8], wf[8];
    #pragma unroll
    for (int i = 0; i < 8; ++i) vf[i] = b2f(vv[i]);
    float4 w0 = *(const float4*)&wm2[q * 8];
    float4 w1 = *(const float4*)&wm2[q * 8 + 4];
    wf[0] = w0.x; wf[1] = w0.y; wf[2] = w0.z; wf[3] = w0.w;
    wf[4] = w1.x; wf[5] = w1.y; wf[6] = w1.z; wf[7] = w1.w;
    const float bb = bm2[0];

    int j = b;
    for (; j + 1 < e; j += 2) {
        int s0 = srcs[j], s1 = srcs[j + 1];
        int e0 = eids[j], e1 = eids[j + 1];
        u16x8 u0 = *(const u16x8*)&Ub[(size_t)s0 * D + q * 8];
        u16x8 u1 = *(const u16x8*)&Ub[(size_t)s1 * D + q * 8];
        float p0 = 0.f, p1 = 0.f;
        #pragma unroll
        for (int i = 0; i < 8; ++i) {
            p0 += fmaxf(b2f(u0[i]) + vf[i], 0.0f) * wf[i];
            p1 += fmaxf(b2f(u1[i]) + vf[i], 0.0f) * wf[i];
        }
        #pragma unroll
        for (int off = 1; off < 16; off <<= 1) {
            p0 += __shfl_xor(p0, off);
            p1 += __shfl_xor(p1, off);
        }
        if (q == 0) {
            out[e0] = 1.0f / (1.0f + expf(-(p0 + bb)));
            out[e1] = 1.0f / (1.0f + expf(-(p1 + bb)));
        }
    }
    if (j < e) {
        int s0 = srcs[j], e0 = eids[j];
        u16x8 u0 = *(const u16x8*)&Ub[(size_t)s0 * D + q * 8];
        float p0 = 0.f;
        #pragma unroll
        for (int i = 0; i < 8; ++i) p0 += fmaxf(b2f(u0[i]) + vf[i], 0.0f) * wf[i];
        #pragma unroll
        for (int off = 1; off < 16; off <<= 1) p0 += __shfl_xor(p0, off);
        if (q == 0) out[e0] = 1.0f / (1.0f + expf(-(p0 + bb)));
    }
}

extern "C" void kernel_launch(void* const* d_in, const int* in_sizes, int n_in,
                              void* d_out, int out_size, void* d_ws, size_t ws_size,
                              hipStream_t stream) {
    const float* x   = (const float*)d_in[0];
    const int*   ei  = (const int*)d_in[1];
    const int*   src = ei;
    const int*   dst = ei + NE;
    const float* W1l = (const float*)d_in[2];
    const float* b1l = (const float*)d_in[3];
    const float* W1r = (const float*)d_in[4];
    const float* W2l = (const float*)d_in[5];
    const float* b2l = (const float*)d_in[6];
    const float* W2r = (const float*)d_in[7];
    const float* Wm1 = (const float*)d_in[8];
    const float* bm1 = (const float*)d_in[9];
    const float* Wm2 = (const float*)d_in[10];
    const float* bm2 = (const float*)d_in[11];
    float* out = (float*)d_out;

    char* ws = (char*)d_ws;
    int* rs   = (int*)(ws + OFF_RS);
    int* cnt  = (int*)(ws + OFF_CNT);
    int* cur  = (int*)(ws + OFF_CUR);    // row_end after scatter_idx
    int* bsum = (int*)(ws + OFF_BS);
    unsigned short* wb = (unsigned short*)(ws + OFF_WB);
    int* srcs = (int*)(ws + OFF_SRC);
    int* eids = (int*)(ws + OFF_EID);
    unsigned short* B0 = (unsigned short*)(ws + OFF_B0);  // xb, later Vb
    unsigned short* B1 = (unsigned short*)(ws + OFF_B1);  // aggb
    unsigned short* B2 = (unsigned short*)(ws + OFF_B2);  // h1b
    unsigned short* B3 = (unsigned short*)(ws + OFF_B3);  // Ub

    unsigned short* W1lb = wb;
    unsigned short* W1rb = wb + 16384;
    unsigned short* W2lb = wb + 32768;
    unsigned short* W2rb = wb + 49152;
    unsigned short* Wm1b = wb + 65536;

    const int NB = 391;  // ceil(NN/256)

    hipMemsetAsync(cnt, 0, NN * sizeof(int), stream);
    k_cvt<<<(NN * D / 4 + 255) / 256, 256, 0, stream>>>(x, B0, NN * D / 4);
    k_cvt_w<<<384, 256, 0, stream>>>(W1l, W1r, W2l, W2r, Wm1, wb);
    k_hist<<<(NE + 255) / 256, 256, 0, stream>>>(dst, cnt);
    k_scan1<<<NB, 256, 0, stream>>>(cnt, bsum);
    k_scan2<<<1, 512, 0, stream>>>(bsum, NB);
    k_scan3<<<NB, 256, 0, stream>>>(cnt, bsum, rs, cur);
    k_scatter_idx<<<(NE + 255) / 256, 256, 0, stream>>>(src, dst, cur, srcs, eids);

    k_agg<<<(NN * 16 + 255) / 256, 256, 0, stream>>>(B0, rs, cur, srcs, B1);
    k_conv_mfma<<<NN / 32, 256, 0, stream>>>(B1, B0, W1lb, W1rb, b1l, B2);       // h1 -> B2
    k_agg<<<(NN * 16 + 255) / 256, 256, 0, stream>>>(B2, rs, cur, srcs, B1);
    k_conv2uv<<<NN / 32, 256, 0, stream>>>(B1, B2, W2lb, W2rb, b2l,
                                           Wm1b, bm1, B3, B0);                   // U -> B3, V -> B0
    k_edge2<<<(NN * 16 + 255) / 256, 256, 0, stream>>>(B3, B0, rs, cur, srcs, eids,
                                                       Wm2, bm2, out);
}

// Round 6
// 328.352 us; speedup vs baseline: 10.7591x; 1.0767x over previous
//
#include <hip/hip_runtime.h>
#include <math.h>

#define NN 100000
#define NE 800000
#define D 128

typedef __attribute__((ext_vector_type(8))) short bf16x8;
typedef __attribute__((ext_vector_type(8))) unsigned short u16x8;
typedef __attribute__((ext_vector_type(4))) float f32x4;

// ---- workspace layout (bytes) ----
constexpr size_t OFF_RS  = 0;                         // int[NN+1]
constexpr size_t OFF_CNT = 512 * 1024;                // int[NN] histogram
constexpr size_t OFF_CUR = 1024 * 1024;               // int[NN] cursor -> row_end
constexpr size_t OFF_BS  = 1536 * 1024;               // int[512] block sums
constexpr size_t OFF_WB  = 1552 * 1024;               // bf16 weights (98304 elems)
constexpr size_t OFF_SRC = 2 * 1024 * 1024;           // int[NE]
constexpr size_t OFF_EID = 6 * 1024 * 1024;           // int[NE]
constexpr size_t OFF_B0  = 10 * 1024 * 1024;          // bf16[100096*128] xb -> Vb
constexpr size_t OFF_B2  = OFF_B0 + 26 * 1024 * 1024; // h1b
constexpr size_t OFF_B3  = OFF_B2 + 26 * 1024 * 1024; // Ub

__device__ __forceinline__ unsigned short f2b(float f) {
    unsigned u = __builtin_bit_cast(unsigned, f);
    return (unsigned short)((u + 0x7FFFu + ((u >> 16) & 1u)) >> 16);
}
__device__ __forceinline__ float b2f(unsigned short h) {
    unsigned u = ((unsigned)h) << 16;
    return __builtin_bit_cast(float, u);
}

// ---------------- conversions ----------------
__global__ __launch_bounds__(256) void k_cvt(const float* __restrict__ in,
                                             unsigned short* __restrict__ outp,
                                             int n4) {
    int i = blockIdx.x * 256 + threadIdx.x;
    if (i >= n4) return;
    float4 v = *(const float4*)&in[(size_t)i * 4];
    ushort4 o;
    o.x = f2b(v.x); o.y = f2b(v.y); o.z = f2b(v.z); o.w = f2b(v.w);
    *(ushort4*)&outp[(size_t)i * 4] = o;
}

__global__ __launch_bounds__(256) void k_cvt_w(const float* __restrict__ W1l,
                                               const float* __restrict__ W1r,
                                               const float* __restrict__ W2l,
                                               const float* __restrict__ W2r,
                                               const float* __restrict__ Wm1,
                                               unsigned short* __restrict__ outp) {
    int i = blockIdx.x * 256 + threadIdx.x;   // 0..98303
    float v;
    if (i < 16384) v = W1l[i];
    else if (i < 32768) v = W1r[i - 16384];
    else if (i < 49152) v = W2l[i - 32768];
    else if (i < 65536) v = W2r[i - 49152];
    else v = Wm1[i - 65536];
    outp[i] = f2b(v);
}

// ---------------- CSR build ----------------
__global__ __launch_bounds__(256) void k_hist(const int* __restrict__ dst,
                                              int* __restrict__ cnt) {
    int e = blockIdx.x * 256 + threadIdx.x;
    if (e < NE) atomicAdd(&cnt[dst[e]], 1);
}

__global__ __launch_bounds__(256) void k_scan1(const int* __restrict__ cnt,
                                               int* __restrict__ bsum) {
    int i = blockIdx.x * 256 + threadIdx.x;
    int v = (i < NN) ? cnt[i] : 0;
    #pragma unroll
    for (int o = 1; o < 64; o <<= 1) v += __shfl_xor(v, o);
    __shared__ int wsum[4];
    if ((threadIdx.x & 63) == 0) wsum[threadIdx.x >> 6] = v;
    __syncthreads();
    if (threadIdx.x == 0) bsum[blockIdx.x] = wsum[0] + wsum[1] + wsum[2] + wsum[3];
}

__global__ __launch_bounds__(512) void k_scan2(int* __restrict__ bsum, int nb) {
    __shared__ int s[512];
    int t = threadIdx.x;
    int v = (t < nb) ? bsum[t] : 0;
    s[t] = v;
    __syncthreads();
    for (int o = 1; o < 512; o <<= 1) {
        int u = (t >= o) ? s[t - o] : 0;
        __syncthreads();
        s[t] += u;
        __syncthreads();
    }
    if (t < nb) bsum[t] = s[t] - v;   // exclusive
}

__global__ __launch_bounds__(256) void k_scan3(const int* __restrict__ cnt,
                                               const int* __restrict__ bsum,
                                               int* __restrict__ rs,
                                               int* __restrict__ cur) {
    __shared__ int s[256];
    int t = threadIdx.x;
    int i = blockIdx.x * 256 + t;
    int v = (i < NN) ? cnt[i] : 0;
    s[t] = v;
    __syncthreads();
    for (int o = 1; o < 256; o <<= 1) {
        int u = (t >= o) ? s[t - o] : 0;
        __syncthreads();
        s[t] += u;
        __syncthreads();
    }
    int ex = s[t] - v + bsum[blockIdx.x];
    if (i < NN) { rs[i] = ex; cur[i] = ex; }
    if (i == NN - 1) rs[NN] = ex + v;
}

__global__ __launch_bounds__(256) void k_scatter_idx(const int* __restrict__ src,
                                                     const int* __restrict__ dst,
                                                     int* __restrict__ cur,
                                                     int* __restrict__ srcs,
                                                     int* __restrict__ eids) {
    int e = blockIdx.x * 256 + threadIdx.x;
    if (e < NE) {
        int pos = atomicAdd(&cur[dst[e]], 1);
        srcs[pos] = src[e];
        eids[pos] = e;
    }
}

// ---- gather-mean for 32 nodes into LDS tile [32][136] (bf16) ----
__device__ __forceinline__ void gather_mean(const unsigned short* __restrict__ feat,
                                            const int* __restrict__ rs,
                                            const int* __restrict__ re,
                                            const int* __restrict__ srcs,
                                            int n0, unsigned short* agt) {
    const int tid = threadIdx.x;
    const int g = tid >> 4, q = tid & 15;
    #pragma unroll
    for (int half = 0; half < 2; ++half) {
        int n = n0 + half * 16 + g;
        int b = rs[n], e = re[n];
        float a0[8] = {}, a1[8] = {}, a2[8] = {}, a3[8] = {};
        int j = b;
        for (; j + 3 < e; j += 4) {
            int s0 = srcs[j], s1 = srcs[j + 1], s2 = srcs[j + 2], s3 = srcs[j + 3];
            u16x8 v0 = *(const u16x8*)&feat[(size_t)s0 * D + q * 8];
            u16x8 v1 = *(const u16x8*)&feat[(size_t)s1 * D + q * 8];
            u16x8 v2 = *(const u16x8*)&feat[(size_t)s2 * D + q * 8];
            u16x8 v3 = *(const u16x8*)&feat[(size_t)s3 * D + q * 8];
            #pragma unroll
            for (int i = 0; i < 8; ++i) a0[i] += b2f(v0[i]);
            #pragma unroll
            for (int i = 0; i < 8; ++i) a1[i] += b2f(v1[i]);
            #pragma unroll
            for (int i = 0; i < 8; ++i) a2[i] += b2f(v2[i]);
            #pragma unroll
            for (int i = 0; i < 8; ++i) a3[i] += b2f(v3[i]);
        }
        for (; j < e; ++j) {
            int s0 = srcs[j];
            u16x8 v0 = *(const u16x8*)&feat[(size_t)s0 * D + q * 8];
            #pragma unroll
            for (int i = 0; i < 8; ++i) a0[i] += b2f(v0[i]);
        }
        float inv = 1.0f / fmaxf((float)(e - b), 1.0f);
        u16x8 o;
        #pragma unroll
        for (int i = 0; i < 8; ++i) o[i] = f2b((a0[i] + a1[i] + a2[i] + a3[i]) * inv);
        *(u16x8*)&agt[(half * 16 + g) * 136 + q * 8] = o;
    }
}

// ---------------- fused agg + conv1: h1 = relu(mean@W1l^T + b + x@W1r^T) ----
__global__ __launch_bounds__(256) void k_aggconv1(const unsigned short* __restrict__ xb,
                                                  const int* __restrict__ rs,
                                                  const int* __restrict__ re,
                                                  const int* __restrict__ srcs,
                                                  const unsigned short* __restrict__ Wlb,
                                                  const unsigned short* __restrict__ Wrb,
                                                  const float* __restrict__ bias,
                                                  unsigned short* __restrict__ hout) {
    __shared__ unsigned short agt[32 * 136];
    __shared__ unsigned short sto[32 * 136];
    const int tid = threadIdx.x;
    const int n0 = blockIdx.x * 32;

    gather_mean(xb, rs, re, srcs, n0, agt);
    __syncthreads();

    const int wc = tid >> 6, l = tid & 63;
    const int lrow = l & 15, lk = (l >> 4) * 8;
    f32x4 acc[2][2] = {};
    #pragma unroll
    for (int p = 0; p < 2; ++p) {
        const unsigned short* W = p ? Wrb : Wlb;
        #pragma unroll
        for (int ks = 0; ks < 4; ++ks) {
            bf16x8 af0, af1;
            if (p == 0) {
                af0 = *(const bf16x8*)&agt[lrow * 136 + ks * 32 + lk];
                af1 = *(const bf16x8*)&agt[(16 + lrow) * 136 + ks * 32 + lk];
            } else {
                af0 = *(const bf16x8*)&xb[(size_t)(n0 + lrow) * D + ks * 32 + lk];
                af1 = *(const bf16x8*)&xb[(size_t)(n0 + 16 + lrow) * D + ks * 32 + lk];
            }
            #pragma unroll
            for (int nt = 0; nt < 2; ++nt) {
                bf16x8 bfr = *(const bf16x8*)&W[(size_t)(wc * 32 + nt * 16 + lrow) * D + ks * 32 + lk];
                acc[0][nt] = __builtin_amdgcn_mfma_f32_16x16x32_bf16(af0, bfr, acc[0][nt], 0, 0, 0);
                acc[1][nt] = __builtin_amdgcn_mfma_f32_16x16x32_bf16(af1, bfr, acc[1][nt], 0, 0, 0);
            }
        }
    }
    const int orow = (l >> 4) * 4, ocol = l & 15;
    #pragma unroll
    for (int nt = 0; nt < 2; ++nt) {
        float bb = bias[wc * 32 + nt * 16 + ocol];
        #pragma unroll
        for (int mt = 0; mt < 2; ++mt)
            #pragma unroll
            for (int j = 0; j < 4; ++j)
                sto[(mt * 16 + orow + j) * 136 + wc * 32 + nt * 16 + ocol] =
                    f2b(fmaxf(acc[mt][nt][j] + bb, 0.0f));
    }
    __syncthreads();
    #pragma unroll
    for (int it = 0; it < 2; ++it) {
        int r = it * 16 + (tid >> 4);
        int c = (tid & 15) * 8;
        u16x8 v = *(const u16x8*)&sto[r * 136 + c];
        *(u16x8*)&hout[(size_t)(n0 + r) * D + c] = v;
    }
}

// ------- fused agg + conv2 + U/V: h2 stays in LDS, U/V to global -------
__global__ __launch_bounds__(256) void k_aggconv2uv(const unsigned short* __restrict__ h1b,
                                                    const int* __restrict__ rs,
                                                    const int* __restrict__ re,
                                                    const int* __restrict__ srcs,
                                                    const unsigned short* __restrict__ Wlb,
                                                    const unsigned short* __restrict__ Wrb,
                                                    const float* __restrict__ bias,
                                                    const unsigned short* __restrict__ Wm1b,
                                                    const float* __restrict__ bm1,
                                                    unsigned short* __restrict__ Ub,
                                                    unsigned short* __restrict__ Vb) {
    __shared__ unsigned short agt[32 * 136];
    __shared__ unsigned short sto[32 * 136];
    const int tid = threadIdx.x;
    const int n0 = blockIdx.x * 32;

    gather_mean(h1b, rs, re, srcs, n0, agt);
    __syncthreads();

    const int wc = tid >> 6, l = tid & 63;
    const int lrow = l & 15, lk = (l >> 4) * 8;
    const int orow = (l >> 4) * 4, ocol = l & 15;

    {   // conv2 -> h2 tile in sto
        f32x4 acc[2][2] = {};
        #pragma unroll
        for (int p = 0; p < 2; ++p) {
            const unsigned short* W = p ? Wrb : Wlb;
            #pragma unroll
            for (int ks = 0; ks < 4; ++ks) {
                bf16x8 af0, af1;
                if (p == 0) {
                    af0 = *(const bf16x8*)&agt[lrow * 136 + ks * 32 + lk];
                    af1 = *(const bf16x8*)&agt[(16 + lrow) * 136 + ks * 32 + lk];
                } else {
                    af0 = *(const bf16x8*)&h1b[(size_t)(n0 + lrow) * D + ks * 32 + lk];
                    af1 = *(const bf16x8*)&h1b[(size_t)(n0 + 16 + lrow) * D + ks * 32 + lk];
                }
                #pragma unroll
                for (int nt = 0; nt < 2; ++nt) {
                    bf16x8 bfr = *(const bf16x8*)&W[(size_t)(wc * 32 + nt * 16 + lrow) * D + ks * 32 + lk];
                    acc[0][nt] = __builtin_amdgcn_mfma_f32_16x16x32_bf16(af0, bfr, acc[0][nt], 0, 0, 0);
                    acc[1][nt] = __builtin_amdgcn_mfma_f32_16x16x32_bf16(af1, bfr, acc[1][nt], 0, 0, 0);
                }
            }
        }
        #pragma unroll
        for (int nt = 0; nt < 2; ++nt) {
            float bb = bias[wc * 32 + nt * 16 + ocol];
            #pragma unroll
            for (int mt = 0; mt < 2; ++mt)
                #pragma unroll
                for (int j = 0; j < 4; ++j)
                    sto[(mt * 16 + orow + j) * 136 + wc * 32 + nt * 16 + ocol] =
                        f2b(fmaxf(acc[mt][nt][j] + bb, 0.0f));
        }
    }
    __syncthreads();   // (1) h2 complete; agt free from here

    bf16x8 af2[2][4];
    #pragma unroll
    for (int mt = 0; mt < 2; ++mt)
        #pragma unroll
        for (int ks = 0; ks < 4; ++ks)
            af2[mt][ks] = *(const bf16x8*)&sto[(mt * 16 + lrow) * 136 + ks * 32 + lk];

    f32x4 aU[2][2] = {}, aV[2][2] = {};
    #pragma unroll
    for (int ks = 0; ks < 4; ++ks)
        #pragma unroll
        for (int nt = 0; nt < 2; ++nt) {
            bf16x8 bu = *(const bf16x8*)&Wm1b[(size_t)(wc * 32 + nt * 16 + lrow) * 256 + ks * 32 + lk];
            bf16x8 bv = *(const bf16x8*)&Wm1b[(size_t)(wc * 32 + nt * 16 + lrow) * 256 + 128 + ks * 32 + lk];
            #pragma unroll
            for (int mt = 0; mt < 2; ++mt) {
                aU[mt][nt] = __builtin_amdgcn_mfma_f32_16x16x32_bf16(af2[mt][ks], bu, aU[mt][nt], 0, 0, 0);
                aV[mt][nt] = __builtin_amdgcn_mfma_f32_16x16x32_bf16(af2[mt][ks], bv, aV[mt][nt], 0, 0, 0);
            }
        }
    // stage U into agt (agt safe after sync(1))
    #pragma unroll
    for (int nt = 0; nt < 2; ++nt) {
        float bb = bm1[wc * 32 + nt * 16 + ocol];
        #pragma unroll
        for (int mt = 0; mt < 2; ++mt)
            #pragma unroll
            for (int j = 0; j < 4; ++j)
                agt[(mt * 16 + orow + j) * 136 + wc * 32 + nt * 16 + ocol] = f2b(aU[mt][nt][j] + bb);
    }
    __syncthreads();   // (2) all af2 reads done, U staged
    // store U; stage V into sto (overwrites h2, safe after sync(2))
    #pragma unroll
    for (int it = 0; it < 2; ++it) {
        int r = it * 16 + (tid >> 4);
        int c = (tid & 15) * 8;
        u16x8 v = *(const u16x8*)&agt[r * 136 + c];
        *(u16x8*)&Ub[(size_t)(n0 + r) * D + c] = v;
    }
    #pragma unroll
    for (int nt = 0; nt < 2; ++nt) {
        #pragma unroll
        for (int mt = 0; mt < 2; ++mt)
            #pragma unroll
            for (int j = 0; j < 4; ++j)
                sto[(mt * 16 + orow + j) * 136 + wc * 32 + nt * 16 + ocol] = f2b(aV[mt][nt][j]);
    }
    __syncthreads();   // (3)
    #pragma unroll
    for (int it = 0; it < 2; ++it) {
        int r = it * 16 + (tid >> 4);
        int c = (tid & 15) * 8;
        u16x8 v = *(const u16x8*)&sto[r * 136 + c];
        *(u16x8*)&Vb[(size_t)(n0 + r) * D + c] = v;
    }
}

// ---------------- edge finalize, dst-grouped, 4-unrolled ----------------
__global__ __launch_bounds__(256) void k_edge2(const unsigned short* __restrict__ Ub,
                                               const unsigned short* __restrict__ Vb,
                                               const int* __restrict__ rs,
                                               const int* __restrict__ re,
                                               const int* __restrict__ srcs,
                                               const int* __restrict__ eids,
                                               const float* __restrict__ wm2,
                                               const float* __restrict__ bm2,
                                               float* __restrict__ out) {
    int t = blockIdx.x * 256 + threadIdx.x;
    int g = t >> 4, q = t & 15;
    if (g >= NN) return;
    int b = rs[g], e = re[g];
    if (b == e) return;
    u16x8 vv = *(const u16x8*)&Vb[(size_t)g * D + q * 8];
    float vf[8], wf[8];
    #pragma unroll
    for (int i = 0; i < 8; ++i) vf[i] = b2f(vv[i]);
    float4 w0 = *(const float4*)&wm2[q * 8];
    float4 w1 = *(const float4*)&wm2[q * 8 + 4];
    wf[0] = w0.x; wf[1] = w0.y; wf[2] = w0.z; wf[3] = w0.w;
    wf[4] = w1.x; wf[5] = w1.y; wf[6] = w1.z; wf[7] = w1.w;
    const float bb = bm2[0];

    int j = b;
    for (; j + 3 < e; j += 4) {
        int s0 = srcs[j], s1 = srcs[j + 1], s2 = srcs[j + 2], s3 = srcs[j + 3];
        int e0 = eids[j], e1 = eids[j + 1], e2 = eids[j + 2], e3 = eids[j + 3];
        u16x8 u0 = *(const u16x8*)&Ub[(size_t)s0 * D + q * 8];
        u16x8 u1 = *(const u16x8*)&Ub[(size_t)s1 * D + q * 8];
        u16x8 u2 = *(const u16x8*)&Ub[(size_t)s2 * D + q * 8];
        u16x8 u3 = *(const u16x8*)&Ub[(size_t)s3 * D + q * 8];
        float p0 = 0.f, p1 = 0.f, p2 = 0.f, p3 = 0.f;
        #pragma unroll
        for (int i = 0; i < 8; ++i) {
            p0 += fmaxf(b2f(u0[i]) + vf[i], 0.0f) * wf[i];
            p1 += fmaxf(b2f(u1[i]) + vf[i], 0.0f) * wf[i];
            p2 += fmaxf(b2f(u2[i]) + vf[i], 0.0f) * wf[i];
            p3 += fmaxf(b2f(u3[i]) + vf[i], 0.0f) * wf[i];
        }
        #pragma unroll
        for (int off = 1; off < 16; off <<= 1) {
            p0 += __shfl_xor(p0, off);
            p1 += __shfl_xor(p1, off);
            p2 += __shfl_xor(p2, off);
            p3 += __shfl_xor(p3, off);
        }
        if (q == 0) {
            out[e0] = 1.0f / (1.0f + expf(-(p0 + bb)));
            out[e1] = 1.0f / (1.0f + expf(-(p1 + bb)));
            out[e2] = 1.0f / (1.0f + expf(-(p2 + bb)));
            out[e3] = 1.0f / (1.0f + expf(-(p3 + bb)));
        }
    }
    for (; j < e; ++j) {
        int s0 = srcs[j], e0 = eids[j];
        u16x8 u0 = *(const u16x8*)&Ub[(size_t)s0 * D + q * 8];
        float p0 = 0.f;
        #pragma unroll
        for (int i = 0; i < 8; ++i) p0 += fmaxf(b2f(u0[i]) + vf[i], 0.0f) * wf[i];
        #pragma unroll
        for (int off = 1; off < 16; off <<= 1) p0 += __shfl_xor(p0, off);
        if (q == 0) out[e0] = 1.0f / (1.0f + expf(-(p0 + bb)));
    }
}

extern "C" void kernel_launch(void* const* d_in, const int* in_sizes, int n_in,
                              void* d_out, int out_size, void* d_ws, size_t ws_size,
                              hipStream_t stream) {
    const float* x   = (const float*)d_in[0];
    const int*   ei  = (const int*)d_in[1];
    const int*   src = ei;
    const int*   dst = ei + NE;
    const float* W1l = (const float*)d_in[2];
    const float* b1l = (const float*)d_in[3];
    const float* W1r = (const float*)d_in[4];
    const float* W2l = (const float*)d_in[5];
    const float* b2l = (const float*)d_in[6];
    const float* W2r = (const float*)d_in[7];
    const float* Wm1 = (const float*)d_in[8];
    const float* bm1 = (const float*)d_in[9];
    const float* Wm2 = (const float*)d_in[10];
    const float* bm2 = (const float*)d_in[11];
    float* out = (float*)d_out;

    char* ws = (char*)d_ws;
    int* rs   = (int*)(ws + OFF_RS);
    int* cnt  = (int*)(ws + OFF_CNT);
    int* cur  = (int*)(ws + OFF_CUR);    // row_end after scatter_idx
    int* bsum = (int*)(ws + OFF_BS);
    unsigned short* wb = (unsigned short*)(ws + OFF_WB);
    int* srcs = (int*)(ws + OFF_SRC);
    int* eids = (int*)(ws + OFF_EID);
    unsigned short* B0 = (unsigned short*)(ws + OFF_B0);  // xb, later Vb
    unsigned short* B2 = (unsigned short*)(ws + OFF_B2);  // h1b
    unsigned short* B3 = (unsigned short*)(ws + OFF_B3);  // Ub

    unsigned short* W1lb = wb;
    unsigned short* W1rb = wb + 16384;
    unsigned short* W2lb = wb + 32768;
    unsigned short* W2rb = wb + 49152;
    unsigned short* Wm1b = wb + 65536;

    const int NB = 391;  // ceil(NN/256)

    hipMemsetAsync(cnt, 0, NN * sizeof(int), stream);
    k_cvt<<<(NN * D / 4 + 255) / 256, 256, 0, stream>>>(x, B0, NN * D / 4);
    k_cvt_w<<<384, 256, 0, stream>>>(W1l, W1r, W2l, W2r, Wm1, wb);
    k_hist<<<(NE + 255) / 256, 256, 0, stream>>>(dst, cnt);
    k_scan1<<<NB, 256, 0, stream>>>(cnt, bsum);
    k_scan2<<<1, 512, 0, stream>>>(bsum, NB);
    k_scan3<<<NB, 256, 0, stream>>>(cnt, bsum, rs, cur);
    k_scatter_idx<<<(NE + 255) / 256, 256, 0, stream>>>(src, dst, cur, srcs, eids);

    k_aggconv1<<<NN / 32, 256, 0, stream>>>(B0, rs, cur, srcs, W1lb, W1rb, b1l, B2);   // h1 -> B2
    k_aggconv2uv<<<NN / 32, 256, 0, stream>>>(B2, rs, cur, srcs, W2lb, W2rb, b2l,
                                              Wm1b, bm1, B3, B0);                      // U -> B3, V -> B0
    k_edge2<<<(NN * 16 + 255) / 256, 256, 0, stream>>>(B3, B0, rs, cur, srcs, eids,
                                                       Wm2, bm2, out);
}